// Round 1
// baseline (10024.551 us; speedup 1.0000x reference)
//
#include <hip/hip_runtime.h>
#include <hip/hip_bf16.h>

typedef __hip_bfloat16 bf16;

#define HH 384
#define HW (384*384)
#define PADO 15          // output pad offset (15,16)
#define OV 353           // valid conv output extent
#define TY 64            // out rows per block
#define TXC 128          // out cols per block
#define IN_ROWS 95       // TY + 31
#define IN_COLS 160      // TXC + 31 = 159, pad to 160
#define SSTR 164         // LDS row stride in floats (pad for bank spread, keeps 16B align)

__device__ inline float b2f(bf16 v){ return __bfloat162float(v); }
__device__ inline bf16  f2b(float v){ return __float2bfloat16(v); }
__device__ inline float sigm(float x){ return 1.f/(1.f+__expf(-x)); }

// ---------------- K1: ci = sigmoid(pad1(conv3x3(inputs)+ic_b)), border = 0.5 ----------------
__global__ __launch_bounds__(256) void ci_kernel(const float* __restrict__ in,
                                                 const float* __restrict__ icw,
                                                 const float* __restrict__ icb,
                                                 bf16* __restrict__ ci)
{
    __shared__ float sw[108];
    __shared__ float sb[4];
    int tid = threadIdx.x;
    if (tid < 108) sw[tid] = icw[tid];
    if (tid < 4)   sb[tid] = icb[tid];
    __syncthreads();
    size_t idx = (size_t)blockIdx.x * 256 + tid;
    int x = (int)(idx % HH);
    int y = (int)((idx / HH) % HH);
    int b = (int)(idx / ((size_t)HH * HH));
    float v[4];
    if (y > 0 && y < HH-1 && x > 0 && x < HH-1) {
        float a0 = sb[0], a1 = sb[1], a2 = sb[2], a3 = sb[3];
        for (int ic = 0; ic < 3; ic++) {
            #pragma unroll
            for (int dy = 0; dy < 3; dy++) {
                #pragma unroll
                for (int dx = 0; dx < 3; dx++) {
                    float iv = in[((size_t)(b*3+ic)*HH + (y-1+dy))*HH + (x-1+dx)];
                    a0 = fmaf(iv, sw[0*27 + ic*9 + dy*3 + dx], a0);
                    a1 = fmaf(iv, sw[1*27 + ic*9 + dy*3 + dx], a1);
                    a2 = fmaf(iv, sw[2*27 + ic*9 + dy*3 + dx], a2);
                    a3 = fmaf(iv, sw[3*27 + ic*9 + dy*3 + dx], a3);
                }
            }
        }
        v[0]=sigm(a0); v[1]=sigm(a1); v[2]=sigm(a2); v[3]=sigm(a3);
    } else {
        v[0]=v[1]=v[2]=v[3]=0.5f;
    }
    #pragma unroll
    for (int o = 0; o < 4; o++)
        ci[((size_t)(b*4+o)*HH + y)*HH + x] = f2b(v[o]);
}

// ---------------- K2a: conv_feats[b,k,hw] = sum_c fm[b,c,hw]*mc_w[k,c] + mc_b[k] ----------------
__global__ __launch_bounds__(256) void convfeats_kernel(const float* __restrict__ fm,
                                                        const float* __restrict__ mcw,
                                                        const float* __restrict__ mcb,
                                                        float* __restrict__ cf)
{
    __shared__ float sw[256*16];   // [c][k]
    int tid = threadIdx.x;
    int b = blockIdx.x >> 2, chunk = blockIdx.x & 3;
    for (int i = tid; i < 4096; i += 256) {
        int k = i / 256, c = i % 256;
        sw[c*16 + k] = mcw[k*256 + c];
    }
    __syncthreads();
    int hw = chunk*256 + tid;
    float acc[16];
    #pragma unroll
    for (int k = 0; k < 16; k++) acc[k] = mcb[k];
    const float* f = fm + (size_t)b*256*1024 + hw;
    for (int c = 0; c < 256; c++) {
        float v = f[(size_t)c*1024];
        const float4* wp = (const float4*)(sw + c*16);
        #pragma unroll
        for (int q = 0; q < 4; q++) {
            float4 t = wp[q];
            acc[q*4+0] = fmaf(v, t.x, acc[q*4+0]);
            acc[q*4+1] = fmaf(v, t.y, acc[q*4+1]);
            acc[q*4+2] = fmaf(v, t.z, acc[q*4+2]);
            acc[q*4+3] = fmaf(v, t.w, acc[q*4+3]);
        }
    }
    #pragma unroll
    for (int k = 0; k < 16; k++)
        cf[(size_t)b*16384 + k*1024 + hw] = acc[k];
}

// -------- K2c: per (b,k): B=meta@mlW.T+mlb ; C = A@B ; wts = sigmoid(C) (bf16) --------
__global__ __launch_bounds__(256) void wts_kernel(const float* __restrict__ meta,
                                                  const float* __restrict__ mlw,
                                                  const float* __restrict__ mlb,
                                                  const float* __restrict__ cf,
                                                  bf16* __restrict__ wts)
{
    __shared__ float sm[64];
    __shared__ float sA[1024];
    __shared__ float sB[1024];
    int tid = threadIdx.x;
    int b = blockIdx.x >> 4, k = blockIdx.x & 15;
    if (tid < 64) sm[tid] = meta[(size_t)b*16*64 + k*64 + tid];
    #pragma unroll
    for (int q = 0; q < 4; q++)
        sA[q*256 + tid] = cf[(size_t)b*16384 + k*1024 + q*256 + tid];
    __syncthreads();
    #pragma unroll
    for (int q = 0; q < 4; q++) {
        int hw = q*256 + tid;
        const float4* wr = (const float4*)(mlw + (size_t)hw*64);
        float a = mlb[hw];
        #pragma unroll
        for (int d4 = 0; d4 < 16; d4++) {
            float4 t = wr[d4];
            a = fmaf(t.x, sm[d4*4+0], a);
            a = fmaf(t.y, sm[d4*4+1], a);
            a = fmaf(t.z, sm[d4*4+2], a);
            a = fmaf(t.w, sm[d4*4+3], a);
        }
        sB[hw] = a;
    }
    __syncthreads();
    #pragma unroll
    for (int q = 0; q < 4; q++) {
        int il = q*256 + tid;
        int i = il >> 5, l = il & 31;
        float a = 0.f;
        #pragma unroll
        for (int j = 0; j < 32; j++)
            a = fmaf(sA[i*32 + j], sB[j*32 + l], a);
        wts[(size_t)b*16384 + k*1024 + il] = f2b(sigm(a));
    }
}

// ---------------- big 32x32 direct conv (4->4 ch), writes padded 384x384 output ----------------
// out(py,px) interior iff 15<=py<368 && 15<=px<368; value = conv at (py-15,px-15) [+bias]; else 0.
template<bool PER_SAMPLE_W, bool OUT_BF16, bool ADD_BIAS>
__global__ __launch_bounds__(256, 2) void conv32(const bf16* __restrict__ in,     // [B,4,384,384]
                                                 const bf16* __restrict__ w_bf,   // [B,16,1024] if per-sample
                                                 const float* __restrict__ w_f,   // [16,1024] if shared
                                                 const float* __restrict__ bias,  // [4]
                                                 void* __restrict__ outp)
{
    __shared__ __align__(16) float s_in[IN_ROWS * SSTR];
    __shared__ __align__(16) float s_w[4 * 1024];       // [c][ky][kx]

    int blk = blockIdx.x;
    int xt = blk % 3;
    int yt = (blk / 3) % 6;
    int m  = (blk / 18) % 4;
    int b  = blk / 72;
    int x0 = xt * TXC, y0 = yt * TY;
    int tid = threadIdx.x;
    int tx = tid & 15, ty = tid >> 4;

    // stage weights for (b,m): layout i = c*1024 + ky*32 + kx
    for (int i = tid; i < 4096; i += 256) {
        if (PER_SAMPLE_W) s_w[i] = b2f(w_bf[(size_t)b*16384 + m*4096 + i]);
        else              s_w[i] = w_f[m*4096 + i];
    }

    float acc[32];
    #pragma unroll
    for (int i = 0; i < 32; i++) acc[i] = 0.f;

    const bf16* inb = in + (size_t)(b*4) * HW;

    for (int c = 0; c < 4; c++) {
        __syncthreads();
        {   // stage input tile, channel c, zero-guarded
            const bf16* inc = inb + (size_t)c * HW;
            for (int i = tid; i < IN_ROWS * IN_COLS; i += 256) {
                int dy = i / IN_COLS, dx = i % IN_COLS;
                int gy = y0 - PADO + dy, gx = x0 - PADO + dx;
                float v = 0.f;
                if (gy >= 0 && gy < HH && gx >= 0 && gx < HH)
                    v = b2f(inc[(size_t)gy*HH + gx]);
                s_in[dy*SSTR + dx] = v;
            }
        }
        __syncthreads();
        const float* wc = s_w + c*1024;
        for (int ky = 0; ky < 32; ky++) {
            float wf[32];
            #pragma unroll
            for (int i = 0; i < 8; i++) {
                float4 t = *(const float4*)(wc + ky*32 + i*4);
                wf[i*4+0]=t.x; wf[i*4+1]=t.y; wf[i*4+2]=t.z; wf[i*4+3]=t.w;
            }
            #pragma unroll
            for (int rr = 0; rr < 4; rr++) {
                const float* rowp = s_in + (ty*4 + rr + ky)*SSTR + tx*8;
                float w[40];
                #pragma unroll
                for (int i = 0; i < 10; i++) {
                    float4 t = *(const float4*)(rowp + i*4);
                    w[i*4+0]=t.x; w[i*4+1]=t.y; w[i*4+2]=t.z; w[i*4+3]=t.w;
                }
                #pragma unroll
                for (int kx = 0; kx < 32; kx++) {
                    #pragma unroll
                    for (int cc = 0; cc < 8; cc++) {
                        acc[rr*8+cc] = fmaf(w[kx+cc], wf[kx], acc[rr*8+cc]);
                    }
                }
            }
        }
    }

    float bv = ADD_BIAS ? bias[m] : 0.f;
    #pragma unroll
    for (int rr = 0; rr < 4; rr++) {
        int py = y0 + ty*4 + rr;
        int oy = py - PADO;
        bool rowok = (oy >= 0 && oy < OV);
        #pragma unroll
        for (int cc = 0; cc < 8; cc++) {
            int px = x0 + tx*8 + cc;
            int ox = px - PADO;
            float v = (rowok && ox >= 0 && ox < OV) ? (acc[rr*8+cc] + bv) : 0.f;
            size_t o = (size_t)(b*4+m)*HW + (size_t)py*HH + px;
            if constexpr (OUT_BF16) ((bf16*)outp)[o] = f2b(v);
            else                    ((float*)outp)[o] = v;
        }
    }
}

extern "C" void kernel_launch(void* const* d_in, const int* in_sizes, int n_in,
                              void* d_out, int out_size, void* d_ws, size_t ws_size,
                              hipStream_t stream)
{
    const float* inputs = (const float*)d_in[0];
    const float* fm     = (const float*)d_in[1];
    const float* meta   = (const float*)d_in[2];
    const float* mcw    = (const float*)d_in[3];
    const float* mcb    = (const float*)d_in[4];
    const float* mlw    = (const float*)d_in[5];
    const float* mlb    = (const float*)d_in[6];
    const float* icw    = (const float*)d_in[7];
    const float* icb    = (const float*)d_in[8];
    const float* bbw    = (const float*)d_in[9];
    const float* bbb    = (const float*)d_in[10];

    // workspace layout (bytes):
    //   ci     bf16 [32,4,384,384]  37,748,736
    //   mapped bf16 [32,4,384,384]  37,748,736
    //   cf     f32  [32,16,1024]     2,097,152
    //   wts    bf16 [32,16,1024]     1,048,576
    char* ws = (char*)d_ws;
    bf16*  ci     = (bf16*) ws;
    bf16*  mapped = (bf16*)(ws + 37748736);
    float* cf     = (float*)(ws + 2*37748736);
    bf16*  wts    = (bf16*)(ws + 2*37748736 + 2097152);

    ci_kernel<<<18432, 256, 0, stream>>>(inputs, icw, icb, ci);
    convfeats_kernel<<<128, 256, 0, stream>>>(fm, mcw, mcb, cf);
    wts_kernel<<<512, 256, 0, stream>>>(meta, mlw, mlb, cf, wts);
    conv32<true,  true,  false><<<2304, 256, 0, stream>>>(ci, wts, nullptr, nullptr, mapped);
    conv32<false, false, true ><<<2304, 256, 0, stream>>>(mapped, nullptr, bbw, bbb, d_out);
}

// Round 2
// 2413.978 us; speedup vs baseline: 4.1527x; 4.1527x over previous
//
#include <hip/hip_runtime.h>
#include <hip/hip_bf16.h>

typedef __hip_bfloat16 bf16;
typedef __attribute__((ext_vector_type(8))) short short8_t;
typedef __attribute__((ext_vector_type(4))) float f32x4;

#define HH 384
#define HW (384*384)
#define NSLICE 140            // 4 c * 35 ky'
#define TOT_ELEMS (32u*4u*147456u)

__device__ inline float b2f(bf16 v){ return __bfloat162float(v); }
__device__ inline bf16  f2b(float v){ return __float2bfloat16(v); }
__device__ inline float sigm(float x){ return 1.f/(1.f+__expf(-x)); }

// ---------------- K1: ci = sigmoid(pad1(conv3x3(inputs)+ic_b)), border = 0.5 ----------------
__global__ __launch_bounds__(256) void ci_kernel(const float* __restrict__ in,
                                                 const float* __restrict__ icw,
                                                 const float* __restrict__ icb,
                                                 bf16* __restrict__ ci)
{
    __shared__ float sw[108];
    __shared__ float sb[4];
    int tid = threadIdx.x;
    if (tid < 108) sw[tid] = icw[tid];
    if (tid < 4)   sb[tid] = icb[tid];
    __syncthreads();
    size_t idx = (size_t)blockIdx.x * 256 + tid;
    int x = (int)(idx % HH);
    int y = (int)((idx / HH) % HH);
    int b = (int)(idx / ((size_t)HH * HH));
    float v[4];
    if (y > 0 && y < HH-1 && x > 0 && x < HH-1) {
        float a0 = sb[0], a1 = sb[1], a2 = sb[2], a3 = sb[3];
        for (int ic = 0; ic < 3; ic++) {
            #pragma unroll
            for (int dy = 0; dy < 3; dy++) {
                #pragma unroll
                for (int dx = 0; dx < 3; dx++) {
                    float iv = in[((size_t)(b*3+ic)*HH + (y-1+dy))*HH + (x-1+dx)];
                    a0 = fmaf(iv, sw[0*27 + ic*9 + dy*3 + dx], a0);
                    a1 = fmaf(iv, sw[1*27 + ic*9 + dy*3 + dx], a1);
                    a2 = fmaf(iv, sw[2*27 + ic*9 + dy*3 + dx], a2);
                    a3 = fmaf(iv, sw[3*27 + ic*9 + dy*3 + dx], a3);
                }
            }
        }
        v[0]=sigm(a0); v[1]=sigm(a1); v[2]=sigm(a2); v[3]=sigm(a3);
    } else {
        v[0]=v[1]=v[2]=v[3]=0.5f;
    }
    #pragma unroll
    for (int o = 0; o < 4; o++)
        ci[((size_t)(b*4+o)*HH + y)*HH + x] = f2b(v[o]);
}

// ---------------- K2a: conv_feats[b,k,hw] = sum_c fm[b,c,hw]*mc_w[k,c] + mc_b[k] ----------------
__global__ __launch_bounds__(256) void convfeats_kernel(const float* __restrict__ fm,
                                                        const float* __restrict__ mcw,
                                                        const float* __restrict__ mcb,
                                                        float* __restrict__ cf)
{
    __shared__ float sw[256*16];   // [c][k]
    int tid = threadIdx.x;
    int b = blockIdx.x >> 2, chunk = blockIdx.x & 3;
    for (int i = tid; i < 4096; i += 256) {
        int k = i / 256, c = i % 256;
        sw[c*16 + k] = mcw[k*256 + c];
    }
    __syncthreads();
    int hw = chunk*256 + tid;
    float acc[16];
    #pragma unroll
    for (int k = 0; k < 16; k++) acc[k] = mcb[k];
    const float* f = fm + (size_t)b*256*1024 + hw;
    for (int c = 0; c < 256; c++) {
        float v = f[(size_t)c*1024];
        const float4* wp = (const float4*)(sw + c*16);
        #pragma unroll
        for (int q = 0; q < 4; q++) {
            float4 t = wp[q];
            acc[q*4+0] = fmaf(v, t.x, acc[q*4+0]);
            acc[q*4+1] = fmaf(v, t.y, acc[q*4+1]);
            acc[q*4+2] = fmaf(v, t.z, acc[q*4+2]);
            acc[q*4+3] = fmaf(v, t.w, acc[q*4+3]);
        }
    }
    #pragma unroll
    for (int k = 0; k < 16; k++)
        cf[(size_t)b*16384 + k*1024 + hw] = acc[k];
}

// -------- K2c: per (b,k): B=meta@mlW.T+mlb ; C = A@B ; wts = sigmoid(C) (bf16) --------
__global__ __launch_bounds__(256) void wts_kernel(const float* __restrict__ meta,
                                                  const float* __restrict__ mlw,
                                                  const float* __restrict__ mlb,
                                                  const float* __restrict__ cf,
                                                  bf16* __restrict__ wts)
{
    __shared__ float sm[64];
    __shared__ float sA[1024];
    __shared__ float sB[1024];
    int tid = threadIdx.x;
    int b = blockIdx.x >> 4, k = blockIdx.x & 15;
    if (tid < 64) sm[tid] = meta[(size_t)b*16*64 + k*64 + tid];
    #pragma unroll
    for (int q = 0; q < 4; q++)
        sA[q*256 + tid] = cf[(size_t)b*16384 + k*1024 + q*256 + tid];
    __syncthreads();
    #pragma unroll
    for (int q = 0; q < 4; q++) {
        int hw = q*256 + tid;
        const float4* wr = (const float4*)(mlw + (size_t)hw*64);
        float a = mlb[hw];
        #pragma unroll
        for (int d4 = 0; d4 < 16; d4++) {
            float4 t = wr[d4];
            a = fmaf(t.x, sm[d4*4+0], a);
            a = fmaf(t.y, sm[d4*4+1], a);
            a = fmaf(t.z, sm[d4*4+2], a);
            a = fmaf(t.w, sm[d4*4+3], a);
        }
        sB[hw] = a;
    }
    __syncthreads();
    #pragma unroll
    for (int q = 0; q < 4; q++) {
        int il = q*256 + tid;
        int i = il >> 5, l = il & 31;
        float a = 0.f;
        #pragma unroll
        for (int j = 0; j < 32; j++)
            a = fmaf(sA[i*32 + j], sB[j*32 + l], a);
        wts[(size_t)b*16384 + k*1024 + il] = f2b(sigm(a));
    }
}

// -------- A-fragment tables: W'[(m,dy)][c,ky',kx] in MFMA lane order --------
// row r = dy*4+m (dy=r>>2, m=r&3); slice s = c*35+ky'; lane l holds row l&15, kx = 8*(l>>4)+i.
// atab[(b)][s][l][i] = wts[b][m*4+c][ky'-dy][kx]  (0 if ky'-dy outside [0,32))
__global__ __launch_bounds__(256) void atab1_kernel(const ushort* __restrict__ wts,
                                                    ushort* __restrict__ atab)
{
    int g = blockIdx.x*256 + threadIdx.x;         // 32*140*64 threads
    int l = g & 63;
    int s = (g >> 6) % NSLICE;
    int b = g / (NSLICE*64);
    int r = l & 15, dy = r >> 2, m = r & 3;
    int c = s / 35, kyp = s % 35, ky = kyp - dy;
    int kxb = 8 * (l >> 4);
    ushort v[8];
    if (ky >= 0 && ky < 32) {
        const ushort* src = wts + ((size_t)b*16 + (m*4+c))*1024 + ky*32 + kxb;
        #pragma unroll
        for (int i=0;i<8;i++) v[i] = src[i];
    } else {
        #pragma unroll
        for (int i=0;i<8;i++) v[i] = 0;
    }
    __builtin_memcpy(atab + (size_t)g*8, v, 16);
}

__global__ __launch_bounds__(256) void atab2_kernel(const float* __restrict__ bbw,
                                                    ushort* __restrict__ atab)
{
    int g = blockIdx.x*256 + threadIdx.x;         // 140*64 threads
    int l = g & 63;
    int s = g >> 6;
    int r = l & 15, dy = r >> 2, m = r & 3;
    int c = s / 35, kyp = s % 35, ky = kyp - dy;
    int kxb = 8 * (l >> 4);
    ushort v[8];
    if (ky >= 0 && ky < 32) {
        const float* src = bbw + ((size_t)(m*4+c))*1024 + ky*32 + kxb;
        #pragma unroll
        for (int i=0;i<8;i++) { bf16 t = f2b(src[i]); v[i] = *(ushort*)&t; }
    } else {
        #pragma unroll
        for (int i=0;i<8;i++) v[i] = 0;
    }
    __builtin_memcpy(atab + (size_t)g*8, v, 16);
}

// ---------------- MFMA implicit-GEMM 32x32 conv (4->4ch, y-shift packed) ----------------
// grid: 32*89 blocks of 256. wave w covers cols [96w, 96w+96), 6 MFMA column-strips.
// D rows: r=4*(l>>4)+q -> dy=l>>4, m=q. Output written into (15,16)-padded [B,4,384,384].
template<bool PER_B, bool OUT_BF16, bool ADD_BIAS>
__global__ __launch_bounds__(256) void conv32_mfma(const ushort* __restrict__ in,
                                                   const short8_t* __restrict__ atab,
                                                   const float* __restrict__ bias,
                                                   void* __restrict__ outp)
{
    int blk = blockIdx.x;
    int yg = blk % 89, b = blk / 89;
    int yv = yg * 4;
    int tid = threadIdx.x;
    int l = tid & 63, w = tid >> 6;
    int xs = w * 96;
    int lanecol = (l & 15) + 8 * (l >> 4);

    const short8_t* at = atab + (PER_B ? (size_t)b*NSLICE*64 : 0) + l;

    f32x4 acc[6];
    #pragma unroll
    for (int j = 0; j < 6; j++) acc[j] = (f32x4){0.f, 0.f, 0.f, 0.f};

    const unsigned LIM = TOT_ELEMS - 88u;   // max base so base+87 stays in-buffer
    unsigned base0 = (unsigned)b*4u*147456u + (unsigned)yv*384u + (unsigned)xs + (unsigned)lanecol;

    int s = 0;
    for (int c = 0; c < 4; ++c) {
        unsigned rb = base0 + (unsigned)c*147456u;
        for (int kyp = 0; kyp < 35; ++kyp) {
            short8_t af = at[s*64];
            unsigned off = rb > LIM ? LIM : rb;
            const ushort* p = in + off;
            short8_t bfr[6];
            #pragma unroll
            for (int j = 0; j < 6; j++)
                __builtin_memcpy(&bfr[j], p + 16*j, 16);   // unaligned 16B global load
            #pragma unroll
            for (int j = 0; j < 6; j++)
                acc[j] = __builtin_amdgcn_mfma_f32_16x16x32_bf16(af, bfr[j], acc[j], 0, 0, 0);
            rb += 384u;
            ++s;
        }
    }

    int dy = l >> 4, col = l & 15;
    int oy = yv + dy;
    if (oy <= 352) {
        int py = oy + 15;
        #pragma unroll
        for (int j = 0; j < 6; j++) {
            int ox = xs + 16*j + col;
            if (ox <= 352) {
                int px = ox + 15;
                #pragma unroll
                for (int q = 0; q < 4; q++) {
                    float v = acc[j][q];
                    if (ADD_BIAS) v += bias[q];
                    size_t o = ((size_t)(b*4+q))*HW + (size_t)py*HH + px;
                    if constexpr (OUT_BF16) ((bf16*)outp)[o] = f2b(v);
                    else                    ((float*)outp)[o] = v;
                }
            }
        }
    }
}

extern "C" void kernel_launch(void* const* d_in, const int* in_sizes, int n_in,
                              void* d_out, int out_size, void* d_ws, size_t ws_size,
                              hipStream_t stream)
{
    const float* inputs = (const float*)d_in[0];
    const float* fm     = (const float*)d_in[1];
    const float* meta   = (const float*)d_in[2];
    const float* mcw    = (const float*)d_in[3];
    const float* mcb    = (const float*)d_in[4];
    const float* mlw    = (const float*)d_in[5];
    const float* mlb    = (const float*)d_in[6];
    const float* icw    = (const float*)d_in[7];
    const float* icb    = (const float*)d_in[8];
    const float* bbw    = (const float*)d_in[9];
    const float* bbb    = (const float*)d_in[10];

    // workspace layout (bytes):
    //   ci     bf16 [32,4,384,384]   @ 0          37,748,736
    //   mapped bf16 [32,4,384,384]   @ 37748736   37,748,736
    //   cf     f32  [32,16,1024]     @ 75497472    2,097,152
    //   wts    bf16 [32,16,1024]     @ 77594624    1,048,576
    //   atab1  bf16 [32,140,64,8]    @ 78643200    4,587,520
    //   atab2  bf16 [140,64,8]       @ 83230720      143,360
    char* ws = (char*)d_ws;
    bf16*   ci     = (bf16*) ws;
    bf16*   mapped = (bf16*)(ws + 37748736);
    float*  cf     = (float*)(ws + 75497472);
    bf16*   wts    = (bf16*)(ws + 77594624);
    ushort* atab1  = (ushort*)(ws + 78643200);
    ushort* atab2  = (ushort*)(ws + 83230720);

    ci_kernel<<<18432, 256, 0, stream>>>(inputs, icw, icb, ci);
    convfeats_kernel<<<128, 256, 0, stream>>>(fm, mcw, mcb, cf);
    wts_kernel<<<512, 256, 0, stream>>>(meta, mlw, mlb, cf, wts);
    atab1_kernel<<<1120, 256, 0, stream>>>((const ushort*)wts, atab1);
    atab2_kernel<<<35, 256, 0, stream>>>(bbw, atab2);

    hipMemsetAsync(mapped, 0, 37748736, stream);
    conv32_mfma<true, true, false><<<32*89, 256, 0, stream>>>(
        (const ushort*)ci, (const short8_t*)atab1, nullptr, mapped);

    hipMemsetAsync(d_out, 0, (size_t)out_size * 4, stream);
    conv32_mfma<false, false, true><<<32*89, 256, 0, stream>>>(
        (const ushort*)mapped, (const short8_t*)atab2, bbb, d_out);
}

// Round 3
// 1380.152 us; speedup vs baseline: 7.2634x; 1.7491x over previous
//
#include <hip/hip_runtime.h>
#include <hip/hip_bf16.h>

typedef __hip_bfloat16 bf16;
typedef __attribute__((ext_vector_type(8))) short short8_t;
typedef __attribute__((ext_vector_type(4))) float f32x4;

#define HH 384
#define HW (384*384)
#define NSLICE 140            // 4 c * 35 ky'
#define TOT_ELEMS (32u*4u*147456u)

__device__ inline float b2f(bf16 v){ return __bfloat162float(v); }
__device__ inline bf16  f2b(float v){ return __float2bfloat16(v); }
__device__ inline float sigm(float x){ return 1.f/(1.f+__expf(-x)); }

// ---------------- K1: ci = sigmoid(pad1(conv3x3(inputs)+ic_b)), border = 0.5 ----------------
// also writes shifted copy ci1[i] = ci0[i+1] when ci1 != nullptr
__global__ __launch_bounds__(256) void ci_kernel(const float* __restrict__ in,
                                                 const float* __restrict__ icw,
                                                 const float* __restrict__ icb,
                                                 bf16* __restrict__ ci,
                                                 bf16* __restrict__ ci1)
{
    __shared__ float sw[108];
    __shared__ float sb[4];
    int tid = threadIdx.x;
    if (tid < 108) sw[tid] = icw[tid];
    if (tid < 4)   sb[tid] = icb[tid];
    __syncthreads();
    size_t idx = (size_t)blockIdx.x * 256 + tid;
    int x = (int)(idx % HH);
    int y = (int)((idx / HH) % HH);
    int b = (int)(idx / ((size_t)HH * HH));
    float v[4];
    if (y > 0 && y < HH-1 && x > 0 && x < HH-1) {
        float a0 = sb[0], a1 = sb[1], a2 = sb[2], a3 = sb[3];
        for (int ic = 0; ic < 3; ic++) {
            #pragma unroll
            for (int dy = 0; dy < 3; dy++) {
                #pragma unroll
                for (int dx = 0; dx < 3; dx++) {
                    float iv = in[((size_t)(b*3+ic)*HH + (y-1+dy))*HH + (x-1+dx)];
                    a0 = fmaf(iv, sw[0*27 + ic*9 + dy*3 + dx], a0);
                    a1 = fmaf(iv, sw[1*27 + ic*9 + dy*3 + dx], a1);
                    a2 = fmaf(iv, sw[2*27 + ic*9 + dy*3 + dx], a2);
                    a3 = fmaf(iv, sw[3*27 + ic*9 + dy*3 + dx], a3);
                }
            }
        }
        v[0]=sigm(a0); v[1]=sigm(a1); v[2]=sigm(a2); v[3]=sigm(a3);
    } else {
        v[0]=v[1]=v[2]=v[3]=0.5f;
    }
    #pragma unroll
    for (int o = 0; o < 4; o++) {
        size_t ofs = ((size_t)(b*4+o)*HH + y)*HH + x;
        bf16 bv = f2b(v[o]);
        ci[ofs] = bv;
        if (ci1 != nullptr && ofs >= 1) ci1[ofs-1] = bv;
    }
}

// ---------------- K2a: conv_feats[b,k,hw] = sum_c fm[b,c,hw]*mc_w[k,c] + mc_b[k] ----------------
__global__ __launch_bounds__(256) void convfeats_kernel(const float* __restrict__ fm,
                                                        const float* __restrict__ mcw,
                                                        const float* __restrict__ mcb,
                                                        float* __restrict__ cf)
{
    __shared__ float sw[256*16];   // [c][k]
    int tid = threadIdx.x;
    int b = blockIdx.x >> 2, chunk = blockIdx.x & 3;
    for (int i = tid; i < 4096; i += 256) {
        int k = i / 256, c = i % 256;
        sw[c*16 + k] = mcw[k*256 + c];
    }
    __syncthreads();
    int hw = chunk*256 + tid;
    float acc[16];
    #pragma unroll
    for (int k = 0; k < 16; k++) acc[k] = mcb[k];
    const float* f = fm + (size_t)b*256*1024 + hw;
    for (int c = 0; c < 256; c++) {
        float v = f[(size_t)c*1024];
        const float4* wp = (const float4*)(sw + c*16);
        #pragma unroll
        for (int q = 0; q < 4; q++) {
            float4 t = wp[q];
            acc[q*4+0] = fmaf(v, t.x, acc[q*4+0]);
            acc[q*4+1] = fmaf(v, t.y, acc[q*4+1]);
            acc[q*4+2] = fmaf(v, t.z, acc[q*4+2]);
            acc[q*4+3] = fmaf(v, t.w, acc[q*4+3]);
        }
    }
    #pragma unroll
    for (int k = 0; k < 16; k++)
        cf[(size_t)b*16384 + k*1024 + hw] = acc[k];
}

// -------- K2c: per (b,k): B=meta@mlW.T+mlb ; C = A@B ; wts = sigmoid(C) (bf16) --------
__global__ __launch_bounds__(256) void wts_kernel(const float* __restrict__ meta,
                                                  const float* __restrict__ mlw,
                                                  const float* __restrict__ mlb,
                                                  const float* __restrict__ cf,
                                                  bf16* __restrict__ wts)
{
    __shared__ float sm[64];
    __shared__ float sA[1024];
    __shared__ float sB[1024];
    int tid = threadIdx.x;
    int b = blockIdx.x >> 4, k = blockIdx.x & 15;
    if (tid < 64) sm[tid] = meta[(size_t)b*16*64 + k*64 + tid];
    #pragma unroll
    for (int q = 0; q < 4; q++)
        sA[q*256 + tid] = cf[(size_t)b*16384 + k*1024 + q*256 + tid];
    __syncthreads();
    #pragma unroll
    for (int q = 0; q < 4; q++) {
        int hw = q*256 + tid;
        const float4* wr = (const float4*)(mlw + (size_t)hw*64);
        float a = mlb[hw];
        #pragma unroll
        for (int d4 = 0; d4 < 16; d4++) {
            float4 t = wr[d4];
            a = fmaf(t.x, sm[d4*4+0], a);
            a = fmaf(t.y, sm[d4*4+1], a);
            a = fmaf(t.z, sm[d4*4+2], a);
            a = fmaf(t.w, sm[d4*4+3], a);
        }
        sB[hw] = a;
    }
    __syncthreads();
    #pragma unroll
    for (int q = 0; q < 4; q++) {
        int il = q*256 + tid;
        int i = il >> 5, l = il & 31;
        float a = 0.f;
        #pragma unroll
        for (int j = 0; j < 32; j++)
            a = fmaf(sA[i*32 + j], sB[j*32 + l], a);
        wts[(size_t)b*16384 + k*1024 + il] = f2b(sigm(a));
    }
}

// -------- A-fragment tables: W'[(m,dy)][c,ky',kx] in MFMA lane order --------
__global__ __launch_bounds__(256) void atab1_kernel(const ushort* __restrict__ wts,
                                                    ushort* __restrict__ atab)
{
    int g = blockIdx.x*256 + threadIdx.x;         // 32*140*64 threads
    int l = g & 63;
    int s = (g >> 6) % NSLICE;
    int b = g / (NSLICE*64);
    int r = l & 15, dy = r >> 2, m = r & 3;
    int c = s / 35, kyp = s % 35, ky = kyp - dy;
    int kxb = 8 * (l >> 4);
    ushort v[8];
    if (ky >= 0 && ky < 32) {
        const ushort* src = wts + ((size_t)b*16 + (m*4+c))*1024 + ky*32 + kxb;
        #pragma unroll
        for (int i=0;i<8;i++) v[i] = src[i];
    } else {
        #pragma unroll
        for (int i=0;i<8;i++) v[i] = 0;
    }
    __builtin_memcpy(atab + (size_t)g*8, v, 16);
}

__global__ __launch_bounds__(256) void atab2_kernel(const float* __restrict__ bbw,
                                                    ushort* __restrict__ atab)
{
    int g = blockIdx.x*256 + threadIdx.x;         // 140*64 threads
    int l = g & 63;
    int s = g >> 6;
    int r = l & 15, dy = r >> 2, m = r & 3;
    int c = s / 35, kyp = s % 35, ky = kyp - dy;
    int kxb = 8 * (l >> 4);
    ushort v[8];
    if (ky >= 0 && ky < 32) {
        const float* src = bbw + ((size_t)(m*4+c))*1024 + ky*32 + kxb;
        #pragma unroll
        for (int i=0;i<8;i++) { bf16 t = f2b(src[i]); v[i] = *(ushort*)&t; }
    } else {
        #pragma unroll
        for (int i=0;i<8;i++) v[i] = 0;
    }
    __builtin_memcpy(atab + (size_t)g*8, v, 16);
}

// ---------------- MFMA implicit-GEMM 32x32 conv (4->4ch, y-shift packed) ----------------
// BMODE 0: aligned loads via shifted-copy pair (in0, in1[i]=in0[i+1])
// BMODE 1: single copy, aligned dwordx4+dword + v_alignbyte extraction
// WSHIFT: also store shifted copy of output (out1[i] = out0[i+1]) for the next conv
template<int BMODE, bool PER_B, bool OUT_BF16, bool ADD_BIAS, bool WSHIFT>
__global__ __launch_bounds__(256) void conv32_mfma(const ushort* __restrict__ in0,
                                                   const ushort* __restrict__ in1,
                                                   const short8_t* __restrict__ atab,
                                                   const float* __restrict__ bias,
                                                   void* __restrict__ outp,
                                                   bf16* __restrict__ out1)
{
    int blk = blockIdx.x;
    int yg = blk % 89, b = blk / 89;
    int yv = yg * 4;
    int tid = threadIdx.x;
    int l = tid & 63, w = tid >> 6;
    int xs = w * 96;
    int lanecol = (l & 15) + 8 * (l >> 4);
    unsigned parity = (unsigned)(lanecol & 1);

    const short8_t* at = atab + (PER_B ? (size_t)b*NSLICE*64 : 0) + l;
    const ushort* srcp = parity ? in1 : in0;

    f32x4 acc[6];
    #pragma unroll
    for (int j = 0; j < 6; j++) acc[j] = (f32x4){0.f, 0.f, 0.f, 0.f};

    const unsigned LIM  = TOT_ELEMS - 96u;
    const unsigned LIMP = LIM + parity;
    unsigned base0 = (unsigned)b*4u*147456u + (unsigned)yv*384u + (unsigned)xs + (unsigned)lanecol;

    int s = 0;
    for (int c = 0; c < 4; ++c) {
        unsigned rb = base0 + (unsigned)c*147456u;
        for (int kyp = 0; kyp < 35; ++kyp) {
            short8_t af = at[s*64];
            short8_t bfr[6];
            if constexpr (BMODE == 0) {
                unsigned off = rb > LIM ? LIMP : rb;
                const ushort* q = srcp + (off - parity);   // even element index -> 4B aligned
                #pragma unroll
                for (int j = 0; j < 6; j++) {
                    const void* a = __builtin_assume_aligned((const void*)(q + 16*j), 4);
                    __builtin_memcpy(&bfr[j], a, 16);      // global_load_dwordx4
                }
            } else {
                unsigned off = rb > LIM ? LIM : rb;
                unsigned d = (off & 1u) * 2u;
                unsigned e0 = off & ~1u;
                #pragma unroll
                for (int j = 0; j < 6; j++) {
                    const uint* a = (const uint*)__builtin_assume_aligned(
                                        (const void*)(in0 + (e0 + 16u*j)), 4);
                    uint D0 = a[0], D1 = a[1], D2 = a[2], D3 = a[3], D4 = a[4];
                    uint t[4];
                    t[0] = __builtin_amdgcn_alignbyte(D1, D0, d);
                    t[1] = __builtin_amdgcn_alignbyte(D2, D1, d);
                    t[2] = __builtin_amdgcn_alignbyte(D3, D2, d);
                    t[3] = __builtin_amdgcn_alignbyte(D4, D3, d);
                    __builtin_memcpy(&bfr[j], t, 16);
                }
            }
            #pragma unroll
            for (int j = 0; j < 6; j++)
                acc[j] = __builtin_amdgcn_mfma_f32_16x16x32_bf16(af, bfr[j], acc[j], 0, 0, 0);
            rb += 384u;
            ++s;
        }
    }

    int dy = l >> 4, col = l & 15;
    int oy = yv + dy;
    if (oy <= 352) {
        int py = oy + 15;
        #pragma unroll
        for (int j = 0; j < 6; j++) {
            int ox = xs + 16*j + col;
            if (ox <= 352) {
                int px = ox + 15;
                #pragma unroll
                for (int q = 0; q < 4; q++) {
                    float v = acc[j][q];
                    if (ADD_BIAS) v += bias[q];
                    size_t o = ((size_t)(b*4+q))*HW + (size_t)py*HH + px;
                    if constexpr (OUT_BF16) {
                        bf16 bv = f2b(v);
                        ((bf16*)outp)[o] = bv;
                        if constexpr (WSHIFT) out1[o-1] = bv;   // o >= 15*384+15 > 0 always
                    } else {
                        ((float*)outp)[o] = v;
                    }
                }
            }
        }
    }
}

extern "C" void kernel_launch(void* const* d_in, const int* in_sizes, int n_in,
                              void* d_out, int out_size, void* d_ws, size_t ws_size,
                              hipStream_t stream)
{
    const float* inputs = (const float*)d_in[0];
    const float* fm     = (const float*)d_in[1];
    const float* meta   = (const float*)d_in[2];
    const float* mcw    = (const float*)d_in[3];
    const float* mcb    = (const float*)d_in[4];
    const float* mlw    = (const float*)d_in[5];
    const float* mlb    = (const float*)d_in[6];
    const float* icw    = (const float*)d_in[7];
    const float* icb    = (const float*)d_in[8];
    const float* bbw    = (const float*)d_in[9];
    const float* bbb    = (const float*)d_in[10];

    const size_t IMG = 37748736;   // bf16 [32,4,384,384]
    // FULL layout: ci0, ci1, mapped0, mapped1, cf, wts, atab1, atab2
    const size_t FULL_BYTES = 4*IMG + 2097152 + 1048576 + 4587520 + 143360;
    bool full = ws_size >= FULL_BYTES;

    char* ws = (char*)d_ws;
    if (full) {
        bf16*   ci0     = (bf16*) ws;
        bf16*   ci1     = (bf16*)(ws + IMG);
        bf16*   mapped0 = (bf16*)(ws + 2*IMG);
        bf16*   mapped1 = (bf16*)(ws + 3*IMG);
        float*  cf      = (float*)(ws + 4*IMG);
        bf16*   wts     = (bf16*)(ws + 4*IMG + 2097152);
        ushort* atab1   = (ushort*)(ws + 4*IMG + 2097152 + 1048576);
        ushort* atab2   = (ushort*)(ws + 4*IMG + 2097152 + 1048576 + 4587520);

        ci_kernel<<<18432, 256, 0, stream>>>(inputs, icw, icb, ci0, ci1);
        convfeats_kernel<<<128, 256, 0, stream>>>(fm, mcw, mcb, cf);
        wts_kernel<<<512, 256, 0, stream>>>(meta, mlw, mlb, cf, wts);
        atab1_kernel<<<1120, 256, 0, stream>>>((const ushort*)wts, atab1);
        atab2_kernel<<<35, 256, 0, stream>>>(bbw, atab2);

        hipMemsetAsync(mapped0, 0, 2*IMG, stream);   // covers mapped0 + mapped1
        conv32_mfma<0, true, true, false, true><<<32*89, 256, 0, stream>>>(
            (const ushort*)ci0, (const ushort*)ci1, (const short8_t*)atab1,
            nullptr, mapped0, mapped1);

        hipMemsetAsync(d_out, 0, (size_t)out_size * 4, stream);
        conv32_mfma<0, false, false, true, false><<<32*89, 256, 0, stream>>>(
            (const ushort*)mapped0, (const ushort*)mapped1, (const short8_t*)atab2,
            bbb, d_out, nullptr);
    } else {
        bf16*   ci0     = (bf16*) ws;
        bf16*   mapped0 = (bf16*)(ws + IMG);
        float*  cf      = (float*)(ws + 2*IMG);
        bf16*   wts     = (bf16*)(ws + 2*IMG + 2097152);
        ushort* atab1   = (ushort*)(ws + 2*IMG + 2097152 + 1048576);
        ushort* atab2   = (ushort*)(ws + 2*IMG + 2097152 + 1048576 + 4587520);

        ci_kernel<<<18432, 256, 0, stream>>>(inputs, icw, icb, ci0, nullptr);
        convfeats_kernel<<<128, 256, 0, stream>>>(fm, mcw, mcb, cf);
        wts_kernel<<<512, 256, 0, stream>>>(meta, mlw, mlb, cf, wts);
        atab1_kernel<<<1120, 256, 0, stream>>>((const ushort*)wts, atab1);
        atab2_kernel<<<35, 256, 0, stream>>>(bbw, atab2);

        hipMemsetAsync(mapped0, 0, IMG, stream);
        conv32_mfma<1, true, true, false, false><<<32*89, 256, 0, stream>>>(
            (const ushort*)ci0, nullptr, (const short8_t*)atab1,
            nullptr, mapped0, nullptr);

        hipMemsetAsync(d_out, 0, (size_t)out_size * 4, stream);
        conv32_mfma<1, false, false, true, false><<<32*89, 256, 0, stream>>>(
            (const ushort*)mapped0, nullptr, (const short8_t*)atab2,
            bbb, d_out, nullptr);
    }
}

// Round 4
// 1188.761 us; speedup vs baseline: 8.4328x; 1.1610x over previous
//
#include <hip/hip_runtime.h>
#include <hip/hip_bf16.h>

typedef __hip_bfloat16 bf16;
typedef __attribute__((ext_vector_type(8))) short short8_t;
typedef __attribute__((ext_vector_type(4))) float f32x4;
typedef __attribute__((ext_vector_type(16))) float f32x16;

#define HH 384
#define HW (384*384)
#define NSLICE 140
#define TOT_ELEMS (32u*4u*147456u)

__device__ inline float b2f(bf16 v){ return __bfloat162float(v); }
__device__ inline bf16  f2b(float v){ return __float2bfloat16(v); }
__device__ inline float sigm(float x){ return 1.f/(1.f+__expf(-x)); }

// ---------------- K1: ci = sigmoid(pad1(conv3x3(inputs)+ic_b)), border = 0.5 ----------------
__global__ __launch_bounds__(256) void ci_kernel(const float* __restrict__ in,
                                                 const float* __restrict__ icw,
                                                 const float* __restrict__ icb,
                                                 bf16* __restrict__ ci,
                                                 bf16* __restrict__ ci1)
{
    __shared__ float sw[108];
    __shared__ float sb[4];
    int tid = threadIdx.x;
    if (tid < 108) sw[tid] = icw[tid];
    if (tid < 4)   sb[tid] = icb[tid];
    __syncthreads();
    size_t idx = (size_t)blockIdx.x * 256 + tid;
    int x = (int)(idx % HH);
    int y = (int)((idx / HH) % HH);
    int b = (int)(idx / ((size_t)HH * HH));
    float v[4];
    if (y > 0 && y < HH-1 && x > 0 && x < HH-1) {
        float a0 = sb[0], a1 = sb[1], a2 = sb[2], a3 = sb[3];
        for (int ic = 0; ic < 3; ic++) {
            #pragma unroll
            for (int dy = 0; dy < 3; dy++) {
                #pragma unroll
                for (int dx = 0; dx < 3; dx++) {
                    float iv = in[((size_t)(b*3+ic)*HH + (y-1+dy))*HH + (x-1+dx)];
                    a0 = fmaf(iv, sw[0*27 + ic*9 + dy*3 + dx], a0);
                    a1 = fmaf(iv, sw[1*27 + ic*9 + dy*3 + dx], a1);
                    a2 = fmaf(iv, sw[2*27 + ic*9 + dy*3 + dx], a2);
                    a3 = fmaf(iv, sw[3*27 + ic*9 + dy*3 + dx], a3);
                }
            }
        }
        v[0]=sigm(a0); v[1]=sigm(a1); v[2]=sigm(a2); v[3]=sigm(a3);
    } else {
        v[0]=v[1]=v[2]=v[3]=0.5f;
    }
    #pragma unroll
    for (int o = 0; o < 4; o++) {
        size_t ofs = ((size_t)(b*4+o)*HH + y)*HH + x;
        bf16 bv = f2b(v[o]);
        ci[ofs] = bv;
        if (ci1 != nullptr && ofs >= 1) ci1[ofs-1] = bv;
    }
}

// ---------------- K2a: conv_feats ----------------
__global__ __launch_bounds__(256) void convfeats_kernel(const float* __restrict__ fm,
                                                        const float* __restrict__ mcw,
                                                        const float* __restrict__ mcb,
                                                        float* __restrict__ cf)
{
    __shared__ float sw[256*16];   // [c][k]
    int tid = threadIdx.x;
    int b = blockIdx.x >> 2, chunk = blockIdx.x & 3;
    for (int i = tid; i < 4096; i += 256) {
        int k = i / 256, c = i % 256;
        sw[c*16 + k] = mcw[k*256 + c];
    }
    __syncthreads();
    int hw = chunk*256 + tid;
    float acc[16];
    #pragma unroll
    for (int k = 0; k < 16; k++) acc[k] = mcb[k];
    const float* f = fm + (size_t)b*256*1024 + hw;
    for (int c = 0; c < 256; c++) {
        float v = f[(size_t)c*1024];
        const float4* wp = (const float4*)(sw + c*16);
        #pragma unroll
        for (int q = 0; q < 4; q++) {
            float4 t = wp[q];
            acc[q*4+0] = fmaf(v, t.x, acc[q*4+0]);
            acc[q*4+1] = fmaf(v, t.y, acc[q*4+1]);
            acc[q*4+2] = fmaf(v, t.z, acc[q*4+2]);
            acc[q*4+3] = fmaf(v, t.w, acc[q*4+3]);
        }
    }
    #pragma unroll
    for (int k = 0; k < 16; k++)
        cf[(size_t)b*16384 + k*1024 + hw] = acc[k];
}

// -------- K2c: wts = sigmoid((cf)@(meta@mlW.T+mlb)), written with row stride rs, offset off0 --------
__global__ __launch_bounds__(256) void wts_kernel(const float* __restrict__ meta,
                                                  const float* __restrict__ mlw,
                                                  const float* __restrict__ mlb,
                                                  const float* __restrict__ cf,
                                                  bf16* __restrict__ wout,
                                                  int rs, int off0)
{
    __shared__ float sm[64];
    __shared__ float sA[1024];
    __shared__ float sB[1024];
    int tid = threadIdx.x;
    int b = blockIdx.x >> 4, k = blockIdx.x & 15;
    if (tid < 64) sm[tid] = meta[(size_t)b*16*64 + k*64 + tid];
    #pragma unroll
    for (int q = 0; q < 4; q++)
        sA[q*256 + tid] = cf[(size_t)b*16384 + k*1024 + q*256 + tid];
    __syncthreads();
    #pragma unroll
    for (int q = 0; q < 4; q++) {
        int hw = q*256 + tid;
        const float4* wr = (const float4*)(mlw + (size_t)hw*64);
        float a = mlb[hw];
        #pragma unroll
        for (int d4 = 0; d4 < 16; d4++) {
            float4 t = wr[d4];
            a = fmaf(t.x, sm[d4*4+0], a);
            a = fmaf(t.y, sm[d4*4+1], a);
            a = fmaf(t.z, sm[d4*4+2], a);
            a = fmaf(t.w, sm[d4*4+3], a);
        }
        sB[hw] = a;
    }
    __syncthreads();
    #pragma unroll
    for (int q = 0; q < 4; q++) {
        int il = q*256 + tid;
        int i = il >> 5, l = il & 31;
        float a = 0.f;
        #pragma unroll
        for (int j = 0; j < 32; j++)
            a = fmaf(sA[i*32 + j], sB[j*32 + l], a);
        wout[((size_t)b*16 + k)*rs + off0 + il] = f2b(sigm(a));
    }
}

// -------- wpad2: bbw f32[16][32][32] -> bf16 [16][46][32], ky zero-padded by 7/7 --------
__global__ __launch_bounds__(256) void wpad2_kernel(const float* __restrict__ bbw,
                                                    ushort* __restrict__ wpad)
{
    int g = blockIdx.x*256 + threadIdx.x;
    if (g >= 16*1472) return;
    int ch = g / 1472, rem = g % 1472;
    int row = rem >> 5, col = rem & 31;
    int ky = row - 7;
    bf16 v = (ky >= 0 && ky < 32) ? f2b(bbw[ch*1024 + ky*32 + col]) : f2b(0.f);
    wpad[g] = *(ushort*)&v;
}

// ================= main conv: 32x32x16 MFMA, 8 y-shifts packed (M=32 = 4m x 8dy) =================
// Block: 256 thr = 4 waves, wave w -> 96 cols (3 strips of 32). Block covers 8 output rows.
// Grid: 32 b * 45 yb = 1440, XCD-chunk swizzled.
// A from wpad[(b?)16ch][46][32] (ky padded) -> always in-bounds, zero rows kill OOB garbage.
// B per lane: 16B at in[row, x0 + (l&31) + 8*(l>>5) + 16kc], parity-aligned via dual copy.
#define LOADSTEP(c, kyp, A0, A1, B0, B1, B2, B3, B4, B5)                                   \
{                                                                                          \
    unsigned ab = Abase + (unsigned)(c)*1472u + (unsigned)(kyp)*32u;                       \
    __builtin_memcpy(&A0, __builtin_assume_aligned((const void*)(wpad + ab), 4), 16);      \
    __builtin_memcpy(&A1, __builtin_assume_aligned((const void*)(wpad + ab + 16u), 4), 16);\
    unsigned bb = Bbase + (unsigned)(c)*147456u + (unsigned)(kyp)*384u;                    \
    unsigned off = bb > LIM ? LIMP : bb;                                                   \
    const ushort* q_ = srcp + (off - parity);                                              \
    __builtin_memcpy(&B0, __builtin_assume_aligned((const void*)(q_ +  0), 4), 16);        \
    __builtin_memcpy(&B1, __builtin_assume_aligned((const void*)(q_ + 16), 4), 16);        \
    __builtin_memcpy(&B2, __builtin_assume_aligned((const void*)(q_ + 32), 4), 16);        \
    __builtin_memcpy(&B3, __builtin_assume_aligned((const void*)(q_ + 48), 4), 16);        \
    __builtin_memcpy(&B4, __builtin_assume_aligned((const void*)(q_ + 64), 4), 16);        \
    __builtin_memcpy(&B5, __builtin_assume_aligned((const void*)(q_ + 80), 4), 16);        \
}

#define DOMFMA(A0, A1, B0, B1, B2, B3, B4, B5)                                   \
{                                                                                \
    acc0 = __builtin_amdgcn_mfma_f32_32x32x16_bf16(A0, B0, acc0, 0, 0, 0);       \
    acc0 = __builtin_amdgcn_mfma_f32_32x32x16_bf16(A1, B1, acc0, 0, 0, 0);       \
    acc1 = __builtin_amdgcn_mfma_f32_32x32x16_bf16(A0, B2, acc1, 0, 0, 0);       \
    acc1 = __builtin_amdgcn_mfma_f32_32x32x16_bf16(A1, B3, acc1, 0, 0, 0);       \
    acc2 = __builtin_amdgcn_mfma_f32_32x32x16_bf16(A0, B4, acc2, 0, 0, 0);       \
    acc2 = __builtin_amdgcn_mfma_f32_32x32x16_bf16(A1, B5, acc2, 0, 0, 0);       \
}

template<bool PER_B, bool OUT_BF16, bool ADD_BIAS, bool WSHIFT>
__global__ __launch_bounds__(256, 3) void conv32_mfma8(const ushort* __restrict__ in0,
                                                       const ushort* __restrict__ in1,
                                                       const ushort* __restrict__ wpad,
                                                       const float* __restrict__ bias,
                                                       void* __restrict__ outp,
                                                       bf16* __restrict__ out1)
{
    // XCD-chunk swizzle (1440 % 8 == 0)
    int d = blockIdx.x;
    int chunk = (int)gridDim.x >> 3;
    int L = (d & 7) * chunk + (d >> 3);
    int b = L / 45, yb = L % 45;
    int yv = yb * 8;

    int tid = threadIdx.x;
    int l = tid & 63, w = tid >> 6;
    int xs = w * 96;
    int r = l & 31;
    int dyA = r >> 2, mA = r & 3;
    int hi = l >> 5;
    int lanecol = (l & 31) + 8*hi;
    unsigned parity = (unsigned)(l & 1);

    const ushort* srcp = parity ? in1 : in0;

    unsigned Abase = ((unsigned)(PER_B ? b*16 : 0) + (unsigned)(mA*4)) * 1472u
                   + (unsigned)(7 - dyA) * 32u + (unsigned)(8*hi);
    unsigned Bbase = (unsigned)b*589824u + (unsigned)yv*384u + (unsigned)xs + (unsigned)lanecol;

    const unsigned LIM  = TOT_ELEMS - 96u;
    const unsigned LIMP = LIM + parity;

    f32x16 acc0, acc1, acc2;
    #pragma unroll
    for (int i = 0; i < 16; i++) { acc0[i] = 0.f; acc1[i] = 0.f; acc2[i] = 0.f; }

    for (int c = 0; c < 4; ++c) {
        short8_t cA0, cA1, cB0, cB1, cB2, cB3, cB4, cB5;
        short8_t nA0, nA1, nB0, nB1, nB2, nB3, nB4, nB5;
        LOADSTEP(c, 0, cA0, cA1, cB0, cB1, cB2, cB3, cB4, cB5);
        for (int kyp = 0; kyp < 37; kyp += 2) {
            LOADSTEP(c, kyp+1, nA0, nA1, nB0, nB1, nB2, nB3, nB4, nB5);
            DOMFMA(cA0, cA1, cB0, cB1, cB2, cB3, cB4, cB5);
            LOADSTEP(c, kyp+2, cA0, cA1, cB0, cB1, cB2, cB3, cB4, cB5);
            DOMFMA(nA0, nA1, nB0, nB1, nB2, nB3, nB4, nB5);
        }
        DOMFMA(cA0, cA1, cB0, cB1, cB2, cB3, cB4, cB5);   // kyp = 38
    }

    float bv0 = 0.f, bv1 = 0.f, bv2 = 0.f, bv3 = 0.f;
    if (ADD_BIAS) { bv0 = bias[0]; bv1 = bias[1]; bv2 = bias[2]; bv3 = bias[3]; }

    #pragma unroll
    for (int j = 0; j < 3; j++) {
        int ox = xs + 32*j + (l & 31);
        if (ox > 352) continue;
        int px = ox + 15;
        #pragma unroll
        for (int rg = 0; rg < 16; rg++) {
            int m  = rg & 3;
            int dy = 2*(rg >> 2) + hi;
            int oy = yv + dy;
            if (oy > 352) continue;
            int py = oy + 15;
            float v = (j == 0 ? acc0[rg] : (j == 1 ? acc1[rg] : acc2[rg]));
            if (ADD_BIAS) v += (m == 0 ? bv0 : m == 1 ? bv1 : m == 2 ? bv2 : bv3);
            size_t o = ((size_t)(b*4 + m))*HW + (size_t)py*HH + px;
            if constexpr (OUT_BF16) {
                bf16 bvv = f2b(v);
                ((bf16*)outp)[o] = bvv;
                if constexpr (WSHIFT) out1[o-1] = bvv;
            } else {
                ((float*)outp)[o] = v;
            }
        }
    }
}

// ================= fallback (no dual-copy workspace): round-3 BMODE1 kernel =================
__global__ __launch_bounds__(256) void atab1_kernel(const ushort* __restrict__ wts,
                                                    ushort* __restrict__ atab)
{
    int g = blockIdx.x*256 + threadIdx.x;
    int l = g & 63;
    int s = (g >> 6) % NSLICE;
    int b = g / (NSLICE*64);
    int r = l & 15, dy = r >> 2, m = r & 3;
    int c = s / 35, kyp = s % 35, ky = kyp - dy;
    int kxb = 8 * (l >> 4);
    ushort v[8];
    if (ky >= 0 && ky < 32) {
        const ushort* src = wts + ((size_t)b*16 + (m*4+c))*1024 + ky*32 + kxb;
        #pragma unroll
        for (int i=0;i<8;i++) v[i] = src[i];
    } else {
        #pragma unroll
        for (int i=0;i<8;i++) v[i] = 0;
    }
    __builtin_memcpy(atab + (size_t)g*8, v, 16);
}

__global__ __launch_bounds__(256) void atab2_kernel(const float* __restrict__ bbw,
                                                    ushort* __restrict__ atab)
{
    int g = blockIdx.x*256 + threadIdx.x;
    int l = g & 63;
    int s = g >> 6;
    int r = l & 15, dy = r >> 2, m = r & 3;
    int c = s / 35, kyp = s % 35, ky = kyp - dy;
    int kxb = 8 * (l >> 4);
    ushort v[8];
    if (ky >= 0 && ky < 32) {
        const float* src = bbw + ((size_t)(m*4+c))*1024 + ky*32 + kxb;
        #pragma unroll
        for (int i=0;i<8;i++) { bf16 t = f2b(src[i]); v[i] = *(ushort*)&t; }
    } else {
        #pragma unroll
        for (int i=0;i<8;i++) v[i] = 0;
    }
    __builtin_memcpy(atab + (size_t)g*8, v, 16);
}

template<bool PER_B, bool OUT_BF16, bool ADD_BIAS>
__global__ __launch_bounds__(256) void conv32_mfma_fb(const ushort* __restrict__ in0,
                                                      const short8_t* __restrict__ atab,
                                                      const float* __restrict__ bias,
                                                      void* __restrict__ outp)
{
    int blk = blockIdx.x;
    int yg = blk % 89, b = blk / 89;
    int yv = yg * 4;
    int tid = threadIdx.x;
    int l = tid & 63, w = tid >> 6;
    int xs = w * 96;
    int lanecol = (l & 15) + 8 * (l >> 4);

    const short8_t* at = atab + (PER_B ? (size_t)b*NSLICE*64 : 0) + l;

    f32x4 acc[6];
    #pragma unroll
    for (int j = 0; j < 6; j++) acc[j] = (f32x4){0.f, 0.f, 0.f, 0.f};

    const unsigned LIM  = TOT_ELEMS - 96u;
    unsigned base0 = (unsigned)b*589824u + (unsigned)yv*384u + (unsigned)xs + (unsigned)lanecol;

    int s = 0;
    for (int c = 0; c < 4; ++c) {
        unsigned rb = base0 + (unsigned)c*147456u;
        for (int kyp = 0; kyp < 35; ++kyp) {
            short8_t af = at[s*64];
            short8_t bfr[6];
            unsigned off = rb > LIM ? LIM : rb;
            unsigned dsh = (off & 1u) * 2u;
            unsigned e0 = off & ~1u;
            #pragma unroll
            for (int j = 0; j < 6; j++) {
                const uint* a = (const uint*)__builtin_assume_aligned(
                                    (const void*)(in0 + (e0 + 16u*j)), 4);
                uint D0 = a[0], D1 = a[1], D2 = a[2], D3 = a[3], D4 = a[4];
                uint t[4];
                t[0] = __builtin_amdgcn_alignbyte(D1, D0, dsh);
                t[1] = __builtin_amdgcn_alignbyte(D2, D1, dsh);
                t[2] = __builtin_amdgcn_alignbyte(D3, D2, dsh);
                t[3] = __builtin_amdgcn_alignbyte(D4, D3, dsh);
                __builtin_memcpy(&bfr[j], t, 16);
            }
            #pragma unroll
            for (int j = 0; j < 6; j++)
                acc[j] = __builtin_amdgcn_mfma_f32_16x16x32_bf16(af, bfr[j], acc[j], 0, 0, 0);
            rb += 384u;
            ++s;
        }
    }

    int dy = l >> 4, col = l & 15;
    int oy = yv + dy;
    if (oy <= 352) {
        int py = oy + 15;
        #pragma unroll
        for (int j = 0; j < 6; j++) {
            int ox = xs + 16*j + col;
            if (ox <= 352) {
                int px = ox + 15;
                #pragma unroll
                for (int q = 0; q < 4; q++) {
                    float v = acc[j][q];
                    if (ADD_BIAS) v += bias[q];
                    size_t o = ((size_t)(b*4+q))*HW + (size_t)py*HH + px;
                    if constexpr (OUT_BF16) ((bf16*)outp)[o] = f2b(v);
                    else                    ((float*)outp)[o] = v;
                }
            }
        }
    }
}

extern "C" void kernel_launch(void* const* d_in, const int* in_sizes, int n_in,
                              void* d_out, int out_size, void* d_ws, size_t ws_size,
                              hipStream_t stream)
{
    const float* inputs = (const float*)d_in[0];
    const float* fm     = (const float*)d_in[1];
    const float* meta   = (const float*)d_in[2];
    const float* mcw    = (const float*)d_in[3];
    const float* mcb    = (const float*)d_in[4];
    const float* mlw    = (const float*)d_in[5];
    const float* mlb    = (const float*)d_in[6];
    const float* icw    = (const float*)d_in[7];
    const float* icb    = (const float*)d_in[8];
    const float* bbw    = (const float*)d_in[9];
    const float* bbb    = (const float*)d_in[10];

    const size_t IMG = 37748736;       // bf16 [32,4,384,384]
    const size_t CF_B = 2097152;
    const size_t WP1_B = 32*16*1472*2; // 1,507,328
    const size_t WP2_B = 16*1472*2;    // 47,104
    const size_t FULL_BYTES = 4*IMG + CF_B + WP1_B + WP2_B;   // ~154.6 MB

    char* ws = (char*)d_ws;
    if (ws_size >= FULL_BYTES) {
        bf16*   ci0     = (bf16*) ws;
        bf16*   ci1     = (bf16*)(ws + IMG);
        bf16*   mapped0 = (bf16*)(ws + 2*IMG);
        bf16*   mapped1 = (bf16*)(ws + 3*IMG);
        float*  cf      = (float*)(ws + 4*IMG);
        ushort* wpad1   = (ushort*)(ws + 4*IMG + CF_B);
        ushort* wpad2   = (ushort*)(ws + 4*IMG + CF_B + WP1_B);

        ci_kernel<<<18432, 256, 0, stream>>>(inputs, icw, icb, ci0, ci1);
        convfeats_kernel<<<128, 256, 0, stream>>>(fm, mcw, mcb, cf);
        hipMemsetAsync(wpad1, 0, WP1_B, stream);
        wts_kernel<<<512, 256, 0, stream>>>(meta, mlw, mlb, cf, (bf16*)wpad1, 1472, 224);
        wpad2_kernel<<<92, 256, 0, stream>>>(bbw, wpad2);

        hipMemsetAsync(mapped0, 0, 2*IMG, stream);   // mapped0 + mapped1
        conv32_mfma8<true, true, false, true><<<1440, 256, 0, stream>>>(
            (const ushort*)ci0, (const ushort*)ci1, wpad1, nullptr, mapped0, mapped1);

        hipMemsetAsync(d_out, 0, (size_t)out_size * 4, stream);
        conv32_mfma8<false, false, true, false><<<1440, 256, 0, stream>>>(
            (const ushort*)mapped0, (const ushort*)mapped1, wpad2, bbb, d_out, nullptr);
    } else {
        bf16*   ci0     = (bf16*) ws;
        bf16*   mapped0 = (bf16*)(ws + IMG);
        float*  cf      = (float*)(ws + 2*IMG);
        bf16*   wts     = (bf16*)(ws + 2*IMG + CF_B);
        ushort* atab1   = (ushort*)(ws + 2*IMG + CF_B + 1048576);
        ushort* atab2   = (ushort*)(ws + 2*IMG + CF_B + 1048576 + 4587520);

        ci_kernel<<<18432, 256, 0, stream>>>(inputs, icw, icb, ci0, nullptr);
        convfeats_kernel<<<128, 256, 0, stream>>>(fm, mcw, mcb, cf);
        wts_kernel<<<512, 256, 0, stream>>>(meta, mlw, mlb, cf, wts, 1024, 0);
        atab1_kernel<<<1120, 256, 0, stream>>>((const ushort*)wts, atab1);
        atab2_kernel<<<35, 256, 0, stream>>>(bbw, atab2);

        hipMemsetAsync(mapped0, 0, IMG, stream);
        conv32_mfma_fb<true, true, false><<<2848, 256, 0, stream>>>(
            (const ushort*)ci0, (const short8_t*)atab1, nullptr, mapped0);

        hipMemsetAsync(d_out, 0, (size_t)out_size * 4, stream);
        conv32_mfma_fb<false, false, true><<<2848, 256, 0, stream>>>(
            (const ushort*)mapped0, (const short8_t*)atab2, bbb, d_out);
    }
}

// Round 5
// 1185.153 us; speedup vs baseline: 8.4584x; 1.0030x over previous
//
#include <hip/hip_runtime.h>
#include <hip/hip_bf16.h>

typedef __hip_bfloat16 bf16;
typedef __attribute__((ext_vector_type(8))) short short8_t;
typedef __attribute__((ext_vector_type(4))) float f32x4;
typedef __attribute__((ext_vector_type(16))) float f32x16;

#define HH 384
#define HW (384*384)
#define NSLICE 140
#define TOT_ELEMS (32u*4u*147456u)

__device__ inline float b2f(bf16 v){ return __bfloat162float(v); }
__device__ inline bf16  f2b(float v){ return __float2bfloat16(v); }
__device__ inline float sigm(float x){ return 1.f/(1.f+__expf(-x)); }

// ---------------- K1: ci = sigmoid(pad1(conv3x3(inputs)+ic_b)), border = 0.5 ----------------
__global__ __launch_bounds__(256) void ci_kernel(const float* __restrict__ in,
                                                 const float* __restrict__ icw,
                                                 const float* __restrict__ icb,
                                                 bf16* __restrict__ ci,
                                                 bf16* __restrict__ ci1)
{
    __shared__ float sw[108];
    __shared__ float sb[4];
    int tid = threadIdx.x;
    if (tid < 108) sw[tid] = icw[tid];
    if (tid < 4)   sb[tid] = icb[tid];
    __syncthreads();
    size_t idx = (size_t)blockIdx.x * 256 + tid;
    int x = (int)(idx % HH);
    int y = (int)((idx / HH) % HH);
    int b = (int)(idx / ((size_t)HH * HH));
    float v[4];
    if (y > 0 && y < HH-1 && x > 0 && x < HH-1) {
        float a0 = sb[0], a1 = sb[1], a2 = sb[2], a3 = sb[3];
        for (int ic = 0; ic < 3; ic++) {
            #pragma unroll
            for (int dy = 0; dy < 3; dy++) {
                #pragma unroll
                for (int dx = 0; dx < 3; dx++) {
                    float iv = in[((size_t)(b*3+ic)*HH + (y-1+dy))*HH + (x-1+dx)];
                    a0 = fmaf(iv, sw[0*27 + ic*9 + dy*3 + dx], a0);
                    a1 = fmaf(iv, sw[1*27 + ic*9 + dy*3 + dx], a1);
                    a2 = fmaf(iv, sw[2*27 + ic*9 + dy*3 + dx], a2);
                    a3 = fmaf(iv, sw[3*27 + ic*9 + dy*3 + dx], a3);
                }
            }
        }
        v[0]=sigm(a0); v[1]=sigm(a1); v[2]=sigm(a2); v[3]=sigm(a3);
    } else {
        v[0]=v[1]=v[2]=v[3]=0.5f;
    }
    #pragma unroll
    for (int o = 0; o < 4; o++) {
        size_t ofs = ((size_t)(b*4+o)*HH + y)*HH + x;
        bf16 bv = f2b(v[o]);
        ci[ofs] = bv;
        if (ci1 != nullptr && ofs >= 1) ci1[ofs-1] = bv;
    }
}

// ---------------- K2a: conv_feats ----------------
__global__ __launch_bounds__(256) void convfeats_kernel(const float* __restrict__ fm,
                                                        const float* __restrict__ mcw,
                                                        const float* __restrict__ mcb,
                                                        float* __restrict__ cf)
{
    __shared__ float sw[256*16];   // [c][k]
    int tid = threadIdx.x;
    int b = blockIdx.x >> 2, chunk = blockIdx.x & 3;
    for (int i = tid; i < 4096; i += 256) {
        int k = i / 256, c = i % 256;
        sw[c*16 + k] = mcw[k*256 + c];
    }
    __syncthreads();
    int hw = chunk*256 + tid;
    float acc[16];
    #pragma unroll
    for (int k = 0; k < 16; k++) acc[k] = mcb[k];
    const float* f = fm + (size_t)b*256*1024 + hw;
    for (int c = 0; c < 256; c++) {
        float v = f[(size_t)c*1024];
        const float4* wp = (const float4*)(sw + c*16);
        #pragma unroll
        for (int q = 0; q < 4; q++) {
            float4 t = wp[q];
            acc[q*4+0] = fmaf(v, t.x, acc[q*4+0]);
            acc[q*4+1] = fmaf(v, t.y, acc[q*4+1]);
            acc[q*4+2] = fmaf(v, t.z, acc[q*4+2]);
            acc[q*4+3] = fmaf(v, t.w, acc[q*4+3]);
        }
    }
    #pragma unroll
    for (int k = 0; k < 16; k++)
        cf[(size_t)b*16384 + k*1024 + hw] = acc[k];
}

// -------- K2c: wts = sigmoid((cf)@(meta@mlW.T+mlb)), row stride rs, offset off0 --------
__global__ __launch_bounds__(256) void wts_kernel(const float* __restrict__ meta,
                                                  const float* __restrict__ mlw,
                                                  const float* __restrict__ mlb,
                                                  const float* __restrict__ cf,
                                                  bf16* __restrict__ wout,
                                                  int rs, int off0)
{
    __shared__ float sm[64];
    __shared__ float sA[1024];
    __shared__ float sB[1024];
    int tid = threadIdx.x;
    int b = blockIdx.x >> 4, k = blockIdx.x & 15;
    if (tid < 64) sm[tid] = meta[(size_t)b*16*64 + k*64 + tid];
    #pragma unroll
    for (int q = 0; q < 4; q++)
        sA[q*256 + tid] = cf[(size_t)b*16384 + k*1024 + q*256 + tid];
    __syncthreads();
    #pragma unroll
    for (int q = 0; q < 4; q++) {
        int hw = q*256 + tid;
        const float4* wr = (const float4*)(mlw + (size_t)hw*64);
        float a = mlb[hw];
        #pragma unroll
        for (int d4 = 0; d4 < 16; d4++) {
            float4 t = wr[d4];
            a = fmaf(t.x, sm[d4*4+0], a);
            a = fmaf(t.y, sm[d4*4+1], a);
            a = fmaf(t.z, sm[d4*4+2], a);
            a = fmaf(t.w, sm[d4*4+3], a);
        }
        sB[hw] = a;
    }
    __syncthreads();
    #pragma unroll
    for (int q = 0; q < 4; q++) {
        int il = q*256 + tid;
        int i = il >> 5, l = il & 31;
        float a = 0.f;
        #pragma unroll
        for (int j = 0; j < 32; j++)
            a = fmaf(sA[i*32 + j], sB[j*32 + l], a);
        wout[((size_t)b*16 + k)*rs + off0 + il] = f2b(sigm(a));
    }
}

// -------- wpad2: bbw f32[16][32][32] -> bf16 [16][46][32], ky zero-padded by 7/7 --------
__global__ __launch_bounds__(256) void wpad2_kernel(const float* __restrict__ bbw,
                                                    ushort* __restrict__ wpad)
{
    int g = blockIdx.x*256 + threadIdx.x;
    if (g >= 16*1472) return;
    int ch = g / 1472, rem = g % 1472;
    int row = rem >> 5, col = rem & 31;
    int ky = row - 7;
    bf16 v = (ky >= 0 && ky < 32) ? f2b(bbw[ch*1024 + ky*32 + col]) : f2b(0.f);
    wpad[g] = *(ushort*)&v;
}

// ================= main conv: 32x32x16 MFMA, 8 y-shifts, manual depth-3 VMEM pipeline =================
#define G_LOADX4(dst, addr, OFF) \
    asm volatile("global_load_dwordx4 %0, %1, off offset:" OFF : "=v"(dst) : "v"(addr))

#define VMWAIT(N) do { asm volatile("s_waitcnt vmcnt(" N ")" ::: "memory"); \
                       __builtin_amdgcn_sched_barrier(0); } while (0)

#define ISSUE(B0_,B1_,B2_,B3_,B4_,B5_,A0_,A1_, c_, kyp_)                                \
{                                                                                       \
    unsigned bb_  = Bbase + (unsigned)(c_)*147456u + (unsigned)(kyp_)*384u;             \
    unsigned off_ = bb_ > LIM ? LIMP : bb_;                                             \
    const ushort* ba_ = srcp + (off_ - parity);                                         \
    const ushort* aa_ = wpad + (Abase + (unsigned)(c_)*1472u + (unsigned)(kyp_)*32u);   \
    G_LOADX4(B0_, ba_, "0");   G_LOADX4(B1_, ba_, "32");  G_LOADX4(B2_, ba_, "64");     \
    G_LOADX4(B3_, ba_, "96");  G_LOADX4(B4_, ba_, "128"); G_LOADX4(B5_, ba_, "160");    \
    G_LOADX4(A0_, aa_, "0");   G_LOADX4(A1_, aa_, "32");                                \
}

#define DOMFMA(A0, A1, B0, B1, B2, B3, B4, B5)                                   \
{                                                                                \
    acc0 = __builtin_amdgcn_mfma_f32_32x32x16_bf16(A0, B0, acc0, 0, 0, 0);       \
    acc0 = __builtin_amdgcn_mfma_f32_32x32x16_bf16(A1, B1, acc0, 0, 0, 0);       \
    acc1 = __builtin_amdgcn_mfma_f32_32x32x16_bf16(A0, B2, acc1, 0, 0, 0);       \
    acc1 = __builtin_amdgcn_mfma_f32_32x32x16_bf16(A1, B3, acc1, 0, 0, 0);       \
    acc2 = __builtin_amdgcn_mfma_f32_32x32x16_bf16(A0, B4, acc2, 0, 0, 0);       \
    acc2 = __builtin_amdgcn_mfma_f32_32x32x16_bf16(A1, B5, acc2, 0, 0, 0);       \
}

template<bool PER_B, bool OUT_BF16, bool ADD_BIAS, bool WSHIFT>
__global__ __launch_bounds__(256) void conv32_mfma8(const ushort* __restrict__ in0,
                                                    const ushort* __restrict__ in1,
                                                    const ushort* __restrict__ wpad,
                                                    const float* __restrict__ bias,
                                                    void* __restrict__ outp,
                                                    bf16* __restrict__ out1)
{
    // XCD-chunk swizzle (1440 % 8 == 0)
    int d = blockIdx.x;
    int chunk = (int)gridDim.x >> 3;
    int L = (d & 7) * chunk + (d >> 3);
    int b = L / 45, yb = L % 45;
    int yv = yb * 8;

    int tid = threadIdx.x;
    int l = tid & 63, w = tid >> 6;
    int xs = w * 96;
    int r = l & 31;
    int dyA = r >> 2, mA = r & 3;
    int hi = l >> 5;
    int lanecol = (l & 31) + 8*hi;
    unsigned parity = (unsigned)(l & 1);

    const ushort* srcp = parity ? in1 : in0;

    unsigned Abase = ((unsigned)(PER_B ? b*16 : 0) + (unsigned)(mA*4)) * 1472u
                   + (unsigned)(7 - dyA) * 32u + (unsigned)(8*hi);
    unsigned Bbase = (unsigned)b*589824u + (unsigned)yv*384u + (unsigned)xs + (unsigned)lanecol;

    const unsigned LIM  = TOT_ELEMS - 96u;
    const unsigned LIMP = LIM + parity;

    f32x16 acc0, acc1, acc2;
    #pragma unroll
    for (int i = 0; i < 16; i++) { acc0[i] = 0.f; acc1[i] = 0.f; acc2[i] = 0.f; }

    for (int c = 0; c < 4; ++c) {
        short8_t aB0,aB1,aB2,aB3,aB4,aB5,aA0,aA1;
        short8_t bB0,bB1,bB2,bB3,bB4,bB5,bA0,bA1;
        short8_t cB0,cB1,cB2,cB3,cB4,cB5,cA0,cA1;
        ISSUE(aB0,aB1,aB2,aB3,aB4,aB5,aA0,aA1, c, 0);
        ISSUE(bB0,bB1,bB2,bB3,bB4,bB5,bA0,bA1, c, 1);
        for (int g = 0; g < 12; ++g) {
            int k3 = 3*g;
            ISSUE(cB0,cB1,cB2,cB3,cB4,cB5,cA0,cA1, c, k3+2);
            VMWAIT("16");
            DOMFMA(aA0,aA1,aB0,aB1,aB2,aB3,aB4,aB5);
            ISSUE(aB0,aB1,aB2,aB3,aB4,aB5,aA0,aA1, c, k3+3);
            VMWAIT("16");
            DOMFMA(bA0,bA1,bB0,bB1,bB2,bB3,bB4,bB5);
            ISSUE(bB0,bB1,bB2,bB3,bB4,bB5,bA0,bA1, c, k3+4);
            VMWAIT("16");
            DOMFMA(cA0,cA1,cB0,cB1,cB2,cB3,cB4,cB5);
        }
        // after loop: a holds step 36, b holds 37; issue and drain 38
        ISSUE(cB0,cB1,cB2,cB3,cB4,cB5,cA0,cA1, c, 38);
        VMWAIT("16");
        DOMFMA(aA0,aA1,aB0,aB1,aB2,aB3,aB4,aB5);
        VMWAIT("8");
        DOMFMA(bA0,bA1,bB0,bB1,bB2,bB3,bB4,bB5);
        VMWAIT("0");
        DOMFMA(cA0,cA1,cB0,cB1,cB2,cB3,cB4,cB5);
    }

    float bv0 = 0.f, bv1 = 0.f, bv2 = 0.f, bv3 = 0.f;
    if (ADD_BIAS) { bv0 = bias[0]; bv1 = bias[1]; bv2 = bias[2]; bv3 = bias[3]; }

    #pragma unroll
    for (int j = 0; j < 3; j++) {
        int ox = xs + 32*j + (l & 31);
        if (ox > 352) continue;
        int px = ox + 15;
        #pragma unroll
        for (int rg = 0; rg < 16; rg++) {
            int m  = rg & 3;
            int dy = 2*(rg >> 2) + hi;
            int oy = yv + dy;
            if (oy > 352) continue;
            int py = oy + 15;
            float v = (j == 0 ? acc0[rg] : (j == 1 ? acc1[rg] : acc2[rg]));
            if (ADD_BIAS) v += (m == 0 ? bv0 : m == 1 ? bv1 : m == 2 ? bv2 : bv3);
            size_t o = ((size_t)(b*4 + m))*HW + (size_t)py*HH + px;
            if constexpr (OUT_BF16) {
                bf16 bvv = f2b(v);
                ((bf16*)outp)[o] = bvv;
                if constexpr (WSHIFT) out1[o-1] = bvv;
            } else {
                ((float*)outp)[o] = v;
            }
        }
    }
}

// ================= fallback (no dual-copy workspace) =================
__global__ __launch_bounds__(256) void atab1_kernel(const ushort* __restrict__ wts,
                                                    ushort* __restrict__ atab)
{
    int g = blockIdx.x*256 + threadIdx.x;
    int l = g & 63;
    int s = (g >> 6) % NSLICE;
    int b = g / (NSLICE*64);
    int r = l & 15, dy = r >> 2, m = r & 3;
    int c = s / 35, kyp = s % 35, ky = kyp - dy;
    int kxb = 8 * (l >> 4);
    ushort v[8];
    if (ky >= 0 && ky < 32) {
        const ushort* src = wts + ((size_t)b*16 + (m*4+c))*1024 + ky*32 + kxb;
        #pragma unroll
        for (int i=0;i<8;i++) v[i] = src[i];
    } else {
        #pragma unroll
        for (int i=0;i<8;i++) v[i] = 0;
    }
    __builtin_memcpy(atab + (size_t)g*8, v, 16);
}

__global__ __launch_bounds__(256) void atab2_kernel(const float* __restrict__ bbw,
                                                    ushort* __restrict__ atab)
{
    int g = blockIdx.x*256 + threadIdx.x;
    int l = g & 63;
    int s = g >> 6;
    int r = l & 15, dy = r >> 2, m = r & 3;
    int c = s / 35, kyp = s % 35, ky = kyp - dy;
    int kxb = 8 * (l >> 4);
    ushort v[8];
    if (ky >= 0 && ky < 32) {
        const float* src = bbw + ((size_t)(m*4+c))*1024 + ky*32 + kxb;
        #pragma unroll
        for (int i=0;i<8;i++) { bf16 t = f2b(src[i]); v[i] = *(ushort*)&t; }
    } else {
        #pragma unroll
        for (int i=0;i<8;i++) v[i] = 0;
    }
    __builtin_memcpy(atab + (size_t)g*8, v, 16);
}

template<bool PER_B, bool OUT_BF16, bool ADD_BIAS>
__global__ __launch_bounds__(256) void conv32_mfma_fb(const ushort* __restrict__ in0,
                                                      const short8_t* __restrict__ atab,
                                                      const float* __restrict__ bias,
                                                      void* __restrict__ outp)
{
    int blk = blockIdx.x;
    int yg = blk % 89, b = blk / 89;
    int yv = yg * 4;
    int tid = threadIdx.x;
    int l = tid & 63, w = tid >> 6;
    int xs = w * 96;
    int lanecol = (l & 15) + 8 * (l >> 4);

    const short8_t* at = atab + (PER_B ? (size_t)b*NSLICE*64 : 0) + l;

    f32x4 acc[6];
    #pragma unroll
    for (int j = 0; j < 6; j++) acc[j] = (f32x4){0.f, 0.f, 0.f, 0.f};

    const unsigned LIM  = TOT_ELEMS - 96u;
    unsigned base0 = (unsigned)b*589824u + (unsigned)yv*384u + (unsigned)xs + (unsigned)lanecol;

    int s = 0;
    for (int c = 0; c < 4; ++c) {
        unsigned rb = base0 + (unsigned)c*147456u;
        for (int kyp = 0; kyp < 35; ++kyp) {
            short8_t af = at[s*64];
            short8_t bfr[6];
            unsigned off = rb > LIM ? LIM : rb;
            unsigned dsh = (off & 1u) * 2u;
            unsigned e0 = off & ~1u;
            #pragma unroll
            for (int j = 0; j < 6; j++) {
                const uint* a = (const uint*)__builtin_assume_aligned(
                                    (const void*)(in0 + (e0 + 16u*j)), 4);
                uint D0 = a[0], D1 = a[1], D2 = a[2], D3 = a[3], D4 = a[4];
                uint t[4];
                t[0] = __builtin_amdgcn_alignbyte(D1, D0, dsh);
                t[1] = __builtin_amdgcn_alignbyte(D2, D1, dsh);
                t[2] = __builtin_amdgcn_alignbyte(D3, D2, dsh);
                t[3] = __builtin_amdgcn_alignbyte(D4, D3, dsh);
                __builtin_memcpy(&bfr[j], t, 16);
            }
            #pragma unroll
            for (int j = 0; j < 6; j++)
                acc[j] = __builtin_amdgcn_mfma_f32_16x16x32_bf16(af, bfr[j], acc[j], 0, 0, 0);
            rb += 384u;
            ++s;
        }
    }

    int dy = l >> 4, col = l & 15;
    int oy = yv + dy;
    if (oy <= 352) {
        int py = oy + 15;
        #pragma unroll
        for (int j = 0; j < 6; j++) {
            int ox = xs + 16*j + col;
            if (ox <= 352) {
                int px = ox + 15;
                #pragma unroll
                for (int q = 0; q < 4; q++) {
                    float v = acc[j][q];
                    if (ADD_BIAS) v += bias[q];
                    size_t o = ((size_t)(b*4+q))*HW + (size_t)py*HH + px;
                    if constexpr (OUT_BF16) ((bf16*)outp)[o] = f2b(v);
                    else                    ((float*)outp)[o] = v;
                }
            }
        }
    }
}

extern "C" void kernel_launch(void* const* d_in, const int* in_sizes, int n_in,
                              void* d_out, int out_size, void* d_ws, size_t ws_size,
                              hipStream_t stream)
{
    const float* inputs = (const float*)d_in[0];
    const float* fm     = (const float*)d_in[1];
    const float* meta   = (const float*)d_in[2];
    const float* mcw    = (const float*)d_in[3];
    const float* mcb    = (const float*)d_in[4];
    const float* mlw    = (const float*)d_in[5];
    const float* mlb    = (const float*)d_in[6];
    const float* icw    = (const float*)d_in[7];
    const float* icb    = (const float*)d_in[8];
    const float* bbw    = (const float*)d_in[9];
    const float* bbb    = (const float*)d_in[10];

    const size_t IMG = 37748736;       // bf16 [32,4,384,384]
    const size_t CF_B = 2097152;
    const size_t WP1_B = 32*16*1472*2; // 1,507,328
    const size_t WP2_B = 16*1472*2;    // 47,104
    const size_t FULL_BYTES = 4*IMG + CF_B + WP1_B + WP2_B;   // ~154.6 MB

    char* ws = (char*)d_ws;
    if (ws_size >= FULL_BYTES) {
        bf16*   ci0     = (bf16*) ws;
        bf16*   ci1     = (bf16*)(ws + IMG);
        bf16*   mapped0 = (bf16*)(ws + 2*IMG);
        bf16*   mapped1 = (bf16*)(ws + 3*IMG);
        float*  cf      = (float*)(ws + 4*IMG);
        ushort* wpad1   = (ushort*)(ws + 4*IMG + CF_B);
        ushort* wpad2   = (ushort*)(ws + 4*IMG + CF_B + WP1_B);

        ci_kernel<<<18432, 256, 0, stream>>>(inputs, icw, icb, ci0, ci1);
        convfeats_kernel<<<128, 256, 0, stream>>>(fm, mcw, mcb, cf);
        hipMemsetAsync(wpad1, 0, WP1_B, stream);
        wts_kernel<<<512, 256, 0, stream>>>(meta, mlw, mlb, cf, (bf16*)wpad1, 1472, 224);
        wpad2_kernel<<<92, 256, 0, stream>>>(bbw, wpad2);

        hipMemsetAsync(mapped0, 0, 2*IMG, stream);   // mapped0 + mapped1
        conv32_mfma8<true, true, false, true><<<1440, 256, 0, stream>>>(
            (const ushort*)ci0, (const ushort*)ci1, wpad1, nullptr, mapped0, mapped1);

        hipMemsetAsync(d_out, 0, (size_t)out_size * 4, stream);
        conv32_mfma8<false, false, true, false><<<1440, 256, 0, stream>>>(
            (const ushort*)mapped0, (const ushort*)mapped1, wpad2, bbb, d_out, nullptr);
    } else {
        bf16*   ci0     = (bf16*) ws;
        bf16*   mapped0 = (bf16*)(ws + IMG);
        float*  cf      = (float*)(ws + 2*IMG);
        bf16*   wts     = (bf16*)(ws + 2*IMG + CF_B);
        ushort* atab1   = (ushort*)(ws + 2*IMG + CF_B + 1048576);
        ushort* atab2   = (ushort*)(ws + 2*IMG + CF_B + 1048576 + 4587520);

        ci_kernel<<<18432, 256, 0, stream>>>(inputs, icw, icb, ci0, nullptr);
        convfeats_kernel<<<128, 256, 0, stream>>>(fm, mcw, mcb, cf);
        wts_kernel<<<512, 256, 0, stream>>>(meta, mlw, mlb, cf, wts, 1024, 0);
        atab1_kernel<<<1120, 256, 0, stream>>>((const ushort*)wts, atab1);
        atab2_kernel<<<35, 256, 0, stream>>>(bbw, atab2);

        hipMemsetAsync(mapped0, 0, IMG, stream);
        conv32_mfma_fb<true, true, false><<<2848, 256, 0, stream>>>(
            (const ushort*)ci0, (const short8_t*)atab1, nullptr, mapped0);

        hipMemsetAsync(d_out, 0, (size_t)out_size * 4, stream);
        conv32_mfma_fb<false, false, true><<<2848, 256, 0, stream>>>(
            (const ushort*)mapped0, (const short8_t*)atab2, bbb, d_out);
    }
}

// Round 6
// 516.184 us; speedup vs baseline: 19.4205x; 2.2960x over previous
//
#include <hip/hip_runtime.h>
#include <hip/hip_bf16.h>

typedef __hip_bfloat16 bf16;
typedef __attribute__((ext_vector_type(8))) short short8_t;
typedef __attribute__((ext_vector_type(16))) float f32x16;

#define HH 384
#define HW (384*384)
#define TOT_ELEMS (32u*4u*147456u)

__device__ inline float b2f(bf16 v){ return __bfloat162float(v); }
__device__ inline bf16  f2b(float v){ return __float2bfloat16(v); }
__device__ inline float sigm(float x){ return 1.f/(1.f+__expf(-x)); }

__device__ inline short8_t mk8(uint a, uint b, uint c, uint d){
    union { uint u[4]; short8_t s; } t;
    t.u[0]=a; t.u[1]=b; t.u[2]=c; t.u[3]=d; return t.s;
}
__device__ inline uint ab2(uint h, uint l){ return __builtin_amdgcn_alignbyte(h, l, 2); }

// ---------------- K1: ci = sigmoid(pad1(conv3x3(inputs)+ic_b)), border = 0.5 ----------------
__global__ __launch_bounds__(256) void ci_kernel(const float* __restrict__ in,
                                                 const float* __restrict__ icw,
                                                 const float* __restrict__ icb,
                                                 bf16* __restrict__ ci)
{
    __shared__ float sw[108];
    __shared__ float sb[4];
    int tid = threadIdx.x;
    if (tid < 108) sw[tid] = icw[tid];
    if (tid < 4)   sb[tid] = icb[tid];
    __syncthreads();
    size_t idx = (size_t)blockIdx.x * 256 + tid;
    int x = (int)(idx % HH);
    int y = (int)((idx / HH) % HH);
    int b = (int)(idx / ((size_t)HH * HH));
    float v[4];
    if (y > 0 && y < HH-1 && x > 0 && x < HH-1) {
        float a0 = sb[0], a1 = sb[1], a2 = sb[2], a3 = sb[3];
        for (int ic = 0; ic < 3; ic++) {
            #pragma unroll
            for (int dy = 0; dy < 3; dy++) {
                #pragma unroll
                for (int dx = 0; dx < 3; dx++) {
                    float iv = in[((size_t)(b*3+ic)*HH + (y-1+dy))*HH + (x-1+dx)];
                    a0 = fmaf(iv, sw[0*27 + ic*9 + dy*3 + dx], a0);
                    a1 = fmaf(iv, sw[1*27 + ic*9 + dy*3 + dx], a1);
                    a2 = fmaf(iv, sw[2*27 + ic*9 + dy*3 + dx], a2);
                    a3 = fmaf(iv, sw[3*27 + ic*9 + dy*3 + dx], a3);
                }
            }
        }
        v[0]=sigm(a0); v[1]=sigm(a1); v[2]=sigm(a2); v[3]=sigm(a3);
    } else {
        v[0]=v[1]=v[2]=v[3]=0.5f;
    }
    #pragma unroll
    for (int o = 0; o < 4; o++)
        ci[((size_t)(b*4+o)*HH + y)*HH + x] = f2b(v[o]);
}

// ---------------- K2a: conv_feats ----------------
__global__ __launch_bounds__(256) void convfeats_kernel(const float* __restrict__ fm,
                                                        const float* __restrict__ mcw,
                                                        const float* __restrict__ mcb,
                                                        float* __restrict__ cf)
{
    __shared__ float sw[256*16];   // [c][k]
    int tid = threadIdx.x;
    int b = blockIdx.x >> 2, chunk = blockIdx.x & 3;
    for (int i = tid; i < 4096; i += 256) {
        int k = i / 256, c = i % 256;
        sw[c*16 + k] = mcw[k*256 + c];
    }
    __syncthreads();
    int hw = chunk*256 + tid;
    float acc[16];
    #pragma unroll
    for (int k = 0; k < 16; k++) acc[k] = mcb[k];
    const float* f = fm + (size_t)b*256*1024 + hw;
    for (int c = 0; c < 256; c++) {
        float v = f[(size_t)c*1024];
        const float4* wp = (const float4*)(sw + c*16);
        #pragma unroll
        for (int q = 0; q < 4; q++) {
            float4 t = wp[q];
            acc[q*4+0] = fmaf(v, t.x, acc[q*4+0]);
            acc[q*4+1] = fmaf(v, t.y, acc[q*4+1]);
            acc[q*4+2] = fmaf(v, t.z, acc[q*4+2]);
            acc[q*4+3] = fmaf(v, t.w, acc[q*4+3]);
        }
    }
    #pragma unroll
    for (int k = 0; k < 16; k++)
        cf[(size_t)b*16384 + k*1024 + hw] = acc[k];
}

// -------- K2c: wts = sigmoid((cf)@(meta@mlW.T+mlb)) -> bf16 [b][16][1024] --------
__global__ __launch_bounds__(256) void wts_kernel(const float* __restrict__ meta,
                                                  const float* __restrict__ mlw,
                                                  const float* __restrict__ mlb,
                                                  const float* __restrict__ cf,
                                                  bf16* __restrict__ wout)
{
    __shared__ float sm[64];
    __shared__ float sA[1024];
    __shared__ float sB[1024];
    int tid = threadIdx.x;
    int b = blockIdx.x >> 4, k = blockIdx.x & 15;
    if (tid < 64) sm[tid] = meta[(size_t)b*16*64 + k*64 + tid];
    #pragma unroll
    for (int q = 0; q < 4; q++)
        sA[q*256 + tid] = cf[(size_t)b*16384 + k*1024 + q*256 + tid];
    __syncthreads();
    #pragma unroll
    for (int q = 0; q < 4; q++) {
        int hw = q*256 + tid;
        const float4* wr = (const float4*)(mlw + (size_t)hw*64);
        float a = mlb[hw];
        #pragma unroll
        for (int d4 = 0; d4 < 16; d4++) {
            float4 t = wr[d4];
            a = fmaf(t.x, sm[d4*4+0], a);
            a = fmaf(t.y, sm[d4*4+1], a);
            a = fmaf(t.z, sm[d4*4+2], a);
            a = fmaf(t.w, sm[d4*4+3], a);
        }
        sB[hw] = a;
    }
    __syncthreads();
    #pragma unroll
    for (int q = 0; q < 4; q++) {
        int il = q*256 + tid;
        int i = il >> 5, l = il & 31;
        float a = 0.f;
        #pragma unroll
        for (int j = 0; j < 32; j++)
            a = fmaf(sA[i*32 + j], sB[j*32 + l], a);
        wout[(size_t)b*16384 + k*1024 + il] = f2b(sigm(a));
    }
}

// -------- A-fragment tables in MFMA lane order: [b][c][kyp][half][lane][8] --------
// row r (0..31) of the M=32 tile = dyA*4 + mA; ky = kyp - dyA (zero-filled outside [0,32))
__global__ __launch_bounds__(256) void atab1F_kernel(const ushort* __restrict__ wts,
                                                     ushort* __restrict__ out)
{
    int g = blockIdx.x*256 + threadIdx.x;      // 32*4*39*2*64 = 638,976
    int lane = g & 63, half = (g >> 6) & 1;
    int rest = g >> 7;
    int kyp = rest % 39; int rest2 = rest / 39;
    int c = rest2 & 3, b = rest2 >> 2;
    int r = lane & 31, hi = lane >> 5;
    int dyA = r >> 2, mA = r & 3;
    int ch = mA*4 + c, ky = kyp - dyA, kx = 16*half + 8*hi;
    ushort v[8];
    if (ky >= 0 && ky < 32) {
        const ushort* src = wts + ((size_t)b*16 + ch)*1024 + ky*32 + kx;
        #pragma unroll
        for (int i=0;i<8;i++) v[i] = src[i];
    } else {
        #pragma unroll
        for (int i=0;i<8;i++) v[i] = 0;
    }
    __builtin_memcpy(out + (size_t)g*8, v, 16);
}

__global__ __launch_bounds__(256) void atab2F_kernel(const float* __restrict__ bbw,
                                                     ushort* __restrict__ out)
{
    int g = blockIdx.x*256 + threadIdx.x;      // 4*39*2*64 = 19,968
    int lane = g & 63, half = (g >> 6) & 1;
    int rest = g >> 7;
    int kyp = rest % 39;
    int c = rest / 39;
    int r = lane & 31, hi = lane >> 5;
    int dyA = r >> 2, mA = r & 3;
    int ch = mA*4 + c, ky = kyp - dyA, kx = 16*half + 8*hi;
    ushort v[8];
    if (ky >= 0 && ky < 32) {
        const float* src = bbw + (size_t)ch*1024 + ky*32 + kx;
        #pragma unroll
        for (int i=0;i<8;i++) { bf16 t = f2b(src[i]); v[i] = *(ushort*)&t; }
    } else {
        #pragma unroll
        for (int i=0;i<8;i++) v[i] = 0;
    }
    __builtin_memcpy(out + (size_t)g*8, v, 16);
}

// ================= LDS-staged conv: 32x32x16 MFMA, 8 y-shifts packed =================
// Block 256 thr = 4 waves, wave w -> cols [96w, 96w+96). Block covers 8 output rows.
// LDS: 39 rows x (448 el copy0 + 448 el copy1(shift+1)) bf16 = 69,888 B.
// B frags: 24 ds_read_b32/K-step, <=2-way bank alias (free). A frags: 2 consecutive-lane
// dwordx4 from atabF (TA fast path), depth-2 asm pipeline with vmcnt(2).
#define G_LOADX4(dst, addr, OFF) \
    asm volatile("global_load_dwordx4 %0, %1, off offset:" OFF : "=v"(dst) : "v"(addr))

#define VMWAIT(N) do { asm volatile("s_waitcnt vmcnt(" N ")" ::: "memory"); \
                       __builtin_amdgcn_sched_barrier(0); } while (0)

#define ISSUE_A(A0_, A1_, kyp_)                                \
{                                                              \
    const ushort* ap_ = aap + (unsigned)(kyp_)*1024u;          \
    G_LOADX4(A0_, ap_, "0");                                   \
    G_LOADX4(A1_, ap_, "1024");                                \
}

#define STEP(kyp_, A0_, A1_, WN)                                                              \
{                                                                                             \
    const uint* rp_ = swl + (unsigned)(kyp_)*448u;                                            \
    uint b00=rp_[0],  b01=rp_[1],  b02=rp_[2],  b03=rp_[3];                                   \
    uint b10=rp_[8],  b11=rp_[9],  b12=rp_[10], b13=rp_[11];                                  \
    uint b20=rp_[16], b21=rp_[17], b22=rp_[18], b23=rp_[19];                                  \
    uint b30=rp_[24], b31=rp_[25], b32=rp_[26], b33=rp_[27];                                  \
    uint b40=rp_[32], b41=rp_[33], b42=rp_[34], b43=rp_[35];                                  \
    uint b50=rp_[40], b51=rp_[41], b52=rp_[42], b53=rp_[43];                                  \
    VMWAIT(WN);                                                                               \
    acc0 = __builtin_amdgcn_mfma_f32_32x32x16_bf16(A0_, mk8(b00,b01,b02,b03), acc0, 0,0,0);   \
    acc0 = __builtin_amdgcn_mfma_f32_32x32x16_bf16(A1_, mk8(b10,b11,b12,b13), acc0, 0,0,0);   \
    acc1 = __builtin_amdgcn_mfma_f32_32x32x16_bf16(A0_, mk8(b20,b21,b22,b23), acc1, 0,0,0);   \
    acc1 = __builtin_amdgcn_mfma_f32_32x32x16_bf16(A1_, mk8(b30,b31,b32,b33), acc1, 0,0,0);   \
    acc2 = __builtin_amdgcn_mfma_f32_32x32x16_bf16(A0_, mk8(b40,b41,b42,b43), acc2, 0,0,0);   \
    acc2 = __builtin_amdgcn_mfma_f32_32x32x16_bf16(A1_, mk8(b50,b51,b52,b53), acc2, 0,0,0);   \
}

template<bool PER_B, bool OUT_BF16, bool ADD_BIAS>
__global__ __launch_bounds__(256) void conv32_lds(const ushort* __restrict__ in,
                                                  const ushort* __restrict__ atabF,
                                                  const float* __restrict__ bias,
                                                  void* __restrict__ outp)
{
    __shared__ uint sbuf[17472];   // 39 * 448 words

    // XCD-chunk swizzle (1440 % 8 == 0)
    int d = blockIdx.x;
    int chunkg = (int)gridDim.x >> 3;
    int L = (d & 7) * chunkg + (d >> 3);
    int b = L / 45, yb = L % 45;
    int yv = yb * 8;

    int tid = threadIdx.x;
    int l = tid & 63, w = tid >> 6;
    int xs = w * 96;
    int hi = l >> 5;

    int s = xs + (l & 31) + 8*hi;      // start element within staged row
    int p = s & 1;
    const uint* swl = sbuf + (unsigned)(p*224 + ((s - p) >> 1));

    f32x16 acc0, acc1, acc2;
    #pragma unroll
    for (int i = 0; i < 16; i++) { acc0[i] = 0.f; acc1[i] = 0.f; acc2[i] = 0.f; }

    unsigned chbase0 = (unsigned)b*589824u + (unsigned)yv*384u;

    for (int c = 0; c < 4; ++c) {
        if (c) __syncthreads();
        // ---- stage channel c: rows yv..yv+38, 448 el + shifted copy ----
        unsigned chb = chbase0 + (unsigned)c*147456u;
        for (int q = tid; q < 2184; q += 256) {     // 39 rows * 56 chunks of 8 el
            int row = q / 56, k = q - row*56;
            unsigned gi = chb + (unsigned)row*384u + (unsigned)k*8u;
            if (gi > TOT_ELEMS - 16u) gi = TOT_ELEMS - 16u;
            const uint* gp = (const uint*)(in + gi);   // 16B aligned
            uint d0 = gp[0], d1 = gp[1], d2 = gp[2], d3 = gp[3], d4 = gp[4];
            unsigned widx = (unsigned)row*448u + (unsigned)k*4u;
            uint4* w0 = (uint4*)&sbuf[widx];
            uint4* w1 = (uint4*)&sbuf[widx + 224u];
            *w0 = make_uint4(d0, d1, d2, d3);
            *w1 = make_uint4(ab2(d1,d0), ab2(d2,d1), ab2(d3,d2), ab2(d4,d3));
        }
        __syncthreads();

        const ushort* aap = atabF + (size_t)((PER_B ? (b*4 + c) : c) * 39) * 1024 + l*8;
        short8_t Aa0, Aa1, Ab0, Ab1;
        ISSUE_A(Aa0, Aa1, 0);
        #pragma unroll 1
        for (int t = 0; t < 19; ++t) {
            ISSUE_A(Ab0, Ab1, 2*t + 1);
            STEP(2*t,     Aa0, Aa1, "2");
            ISSUE_A(Aa0, Aa1, 2*t + 2);
            STEP(2*t + 1, Ab0, Ab1, "2");
        }
        STEP(38, Aa0, Aa1, "0");
    }

    float bv0 = 0.f, bv1 = 0.f, bv2 = 0.f, bv3 = 0.f;
    if (ADD_BIAS) { bv0 = bias[0]; bv1 = bias[1]; bv2 = bias[2]; bv3 = bias[3]; }

    #pragma unroll
    for (int j = 0; j < 3; j++) {
        int ox = xs + 32*j + (l & 31);
        if (ox > 352) continue;
        int px = ox + 15;
        #pragma unroll
        for (int rg = 0; rg < 16; rg++) {
            int m  = rg & 3;
            int dy = 2*(rg >> 2) + hi;
            int oy = yv + dy;
            if (oy > 352) continue;
            int py = oy + 15;
            float v = (j == 0 ? acc0[rg] : (j == 1 ? acc1[rg] : acc2[rg]));
            if (ADD_BIAS) v += (m == 0 ? bv0 : m == 1 ? bv1 : m == 2 ? bv2 : bv3);
            size_t o = ((size_t)(b*4 + m))*HW + (size_t)py*HH + px;
            if constexpr (OUT_BF16) ((bf16*)outp)[o] = f2b(v);
            else                    ((float*)outp)[o] = v;
        }
    }
}

extern "C" void kernel_launch(void* const* d_in, const int* in_sizes, int n_in,
                              void* d_out, int out_size, void* d_ws, size_t ws_size,
                              hipStream_t stream)
{
    const float* inputs = (const float*)d_in[0];
    const float* fm     = (const float*)d_in[1];
    const float* meta   = (const float*)d_in[2];
    const float* mcw    = (const float*)d_in[3];
    const float* mcb    = (const float*)d_in[4];
    const float* mlw    = (const float*)d_in[5];
    const float* mlb    = (const float*)d_in[6];
    const float* icw    = (const float*)d_in[7];
    const float* icb    = (const float*)d_in[8];
    const float* bbw    = (const float*)d_in[9];
    const float* bbb    = (const float*)d_in[10];

    // workspace layout (bytes):
    //   ci     bf16 [32,4,384,384]      @ 0           37,748,736
    //   mapped bf16 [32,4,384,384]      @ 37,748,736  37,748,736
    //   cf     f32  [32,16,1024]        @ 75,497,472   2,097,152
    //   wts    bf16 [32,16,1024]        @ 77,594,624   1,048,576
    //   atab1F bf16 [32,4,39,2,64,8]    @ 78,643,200  10,223,616
    //   atab2F bf16 [4,39,2,64,8]       @ 88,866,816     319,488
    char* ws = (char*)d_ws;
    bf16*   ci     = (bf16*) ws;
    bf16*   mapped = (bf16*)(ws + 37748736);
    float*  cf     = (float*)(ws + 75497472);
    bf16*   wts    = (bf16*)(ws + 77594624);
    ushort* atab1F = (ushort*)(ws + 78643200);
    ushort* atab2F = (ushort*)(ws + 88866816);

    ci_kernel<<<18432, 256, 0, stream>>>(inputs, icw, icb, ci);
    convfeats_kernel<<<128, 256, 0, stream>>>(fm, mcw, mcb, cf);
    wts_kernel<<<512, 256, 0, stream>>>(meta, mlw, mlb, cf, wts);
    atab1F_kernel<<<2496, 256, 0, stream>>>((const ushort*)wts, atab1F);
    atab2F_kernel<<<78, 256, 0, stream>>>(bbw, atab2F);

    hipMemsetAsync(mapped, 0, 37748736, stream);
    conv32_lds<true, true, false><<<1440, 256, 0, stream>>>(
        (const ushort*)ci, atab1F, nullptr, mapped);

    hipMemsetAsync(d_out, 0, (size_t)out_size * 4, stream);
    conv32_lds<false, false, true><<<1440, 256, 0, stream>>>(
        (const ushort*)mapped, atab2F, bbb, d_out);
}

// Round 8
// 455.443 us; speedup vs baseline: 22.0106x; 1.1334x over previous
//
#include <hip/hip_runtime.h>
#include <hip/hip_bf16.h>

typedef __hip_bfloat16 bf16;
typedef __attribute__((ext_vector_type(8))) short short8_t;
typedef __attribute__((ext_vector_type(16))) float f32x16;

#define HH 384
#define HW (384*384)
#define TOT_ELEMS (32u*4u*147456u)

__device__ inline float b2f(bf16 v){ return __bfloat162float(v); }
__device__ inline bf16  f2b(float v){ return __float2bfloat16(v); }
__device__ inline float sigm(float x){ return 1.f/(1.f+__expf(-x)); }

__device__ inline short8_t mk8(uint a, uint b, uint c, uint d){
    union { uint u[4]; short8_t s; } t;
    t.u[0]=a; t.u[1]=b; t.u[2]=c; t.u[3]=d; return t.s;
}
__device__ inline uint ab2(uint h, uint l){ return __builtin_amdgcn_alignbyte(h, l, 2); }

// ---------------- K1: ci = sigmoid(pad1(conv3x3(inputs)+ic_b)), border = 0.5 ----------------
__global__ __launch_bounds__(256) void ci_kernel(const float* __restrict__ in,
                                                 const float* __restrict__ icw,
                                                 const float* __restrict__ icb,
                                                 bf16* __restrict__ ci)
{
    __shared__ float sw[108];
    __shared__ float sb[4];
    int tid = threadIdx.x;
    if (tid < 108) sw[tid] = icw[tid];
    if (tid < 4)   sb[tid] = icb[tid];
    __syncthreads();
    size_t idx = (size_t)blockIdx.x * 256 + tid;
    int x = (int)(idx % HH);
    int y = (int)((idx / HH) % HH);
    int b = (int)(idx / ((size_t)HH * HH));
    float v[4];
    if (y > 0 && y < HH-1 && x > 0 && x < HH-1) {
        float a0 = sb[0], a1 = sb[1], a2 = sb[2], a3 = sb[3];
        for (int ic = 0; ic < 3; ic++) {
            #pragma unroll
            for (int dy = 0; dy < 3; dy++) {
                #pragma unroll
                for (int dx = 0; dx < 3; dx++) {
                    float iv = in[((size_t)(b*3+ic)*HH + (y-1+dy))*HH + (x-1+dx)];
                    a0 = fmaf(iv, sw[0*27 + ic*9 + dy*3 + dx], a0);
                    a1 = fmaf(iv, sw[1*27 + ic*9 + dy*3 + dx], a1);
                    a2 = fmaf(iv, sw[2*27 + ic*9 + dy*3 + dx], a2);
                    a3 = fmaf(iv, sw[3*27 + ic*9 + dy*3 + dx], a3);
                }
            }
        }
        v[0]=sigm(a0); v[1]=sigm(a1); v[2]=sigm(a2); v[3]=sigm(a3);
    } else {
        v[0]=v[1]=v[2]=v[3]=0.5f;
    }
    #pragma unroll
    for (int o = 0; o < 4; o++)
        ci[((size_t)(b*4+o)*HH + y)*HH + x] = f2b(v[o]);
}

// ---------------- K2a: conv_feats ----------------
__global__ __launch_bounds__(256) void convfeats_kernel(const float* __restrict__ fm,
                                                        const float* __restrict__ mcw,
                                                        const float* __restrict__ mcb,
                                                        float* __restrict__ cf)
{
    __shared__ float sw[256*16];   // [c][k]
    int tid = threadIdx.x;
    int b = blockIdx.x >> 2, chunk = blockIdx.x & 3;
    for (int i = tid; i < 4096; i += 256) {
        int k = i / 256, c = i % 256;
        sw[c*16 + k] = mcw[k*256 + c];
    }
    __syncthreads();
    int hw = chunk*256 + tid;
    float acc[16];
    #pragma unroll
    for (int k = 0; k < 16; k++) acc[k] = mcb[k];
    const float* f = fm + (size_t)b*256*1024 + hw;
    for (int c = 0; c < 256; c++) {
        float v = f[(size_t)c*1024];
        const float4* wp = (const float4*)(sw + c*16);
        #pragma unroll
        for (int q = 0; q < 4; q++) {
            float4 t = wp[q];
            acc[q*4+0] = fmaf(v, t.x, acc[q*4+0]);
            acc[q*4+1] = fmaf(v, t.y, acc[q*4+1]);
            acc[q*4+2] = fmaf(v, t.z, acc[q*4+2]);
            acc[q*4+3] = fmaf(v, t.w, acc[q*4+3]);
        }
    }
    #pragma unroll
    for (int k = 0; k < 16; k++)
        cf[(size_t)b*16384 + k*1024 + hw] = acc[k];
}

// -------- K2c: wts = sigmoid((cf)@(meta@mlW.T+mlb)) -> bf16 [b][16][1024] --------
__global__ __launch_bounds__(256) void wts_kernel(const float* __restrict__ meta,
                                                  const float* __restrict__ mlw,
                                                  const float* __restrict__ mlb,
                                                  const float* __restrict__ cf,
                                                  bf16* __restrict__ wout)
{
    __shared__ float sm[64];
    __shared__ float sA[1024];
    __shared__ float sB[1024];
    int tid = threadIdx.x;
    int b = blockIdx.x >> 4, k = blockIdx.x & 15;
    if (tid < 64) sm[tid] = meta[(size_t)b*16*64 + k*64 + tid];
    #pragma unroll
    for (int q = 0; q < 4; q++)
        sA[q*256 + tid] = cf[(size_t)b*16384 + k*1024 + q*256 + tid];
    __syncthreads();
    #pragma unroll
    for (int q = 0; q < 4; q++) {
        int hw = q*256 + tid;
        const float4* wr = (const float4*)(mlw + (size_t)hw*64);
        float a = mlb[hw];
        #pragma unroll
        for (int d4 = 0; d4 < 16; d4++) {
            float4 t = wr[d4];
            a = fmaf(t.x, sm[d4*4+0], a);
            a = fmaf(t.y, sm[d4*4+1], a);
            a = fmaf(t.z, sm[d4*4+2], a);
            a = fmaf(t.w, sm[d4*4+3], a);
        }
        sB[hw] = a;
    }
    __syncthreads();
    #pragma unroll
    for (int q = 0; q < 4; q++) {
        int il = q*256 + tid;
        int i = il >> 5, l = il & 31;
        float a = 0.f;
        #pragma unroll
        for (int j = 0; j < 32; j++)
            a = fmaf(sA[i*32 + j], sB[j*32 + l], a);
        wout[(size_t)b*16384 + k*1024 + il] = f2b(sigm(a));
    }
}

// -------- A-fragment tables in MFMA lane order: [b][c][kyp][half][lane][8] --------
__global__ __launch_bounds__(256) void atab1F_kernel(const ushort* __restrict__ wts,
                                                     ushort* __restrict__ out)
{
    int g = blockIdx.x*256 + threadIdx.x;      // 32*4*39*2*64 = 638,976
    int lane = g & 63, half = (g >> 6) & 1;
    int rest = g >> 7;
    int kyp = rest % 39; int rest2 = rest / 39;
    int c = rest2 & 3, b = rest2 >> 2;
    int r = lane & 31, hi = lane >> 5;
    int dyA = r >> 2, mA = r & 3;
    int ch = mA*4 + c, ky = kyp - dyA, kx = 16*half + 8*hi;
    ushort v[8];
    if (ky >= 0 && ky < 32) {
        const ushort* src = wts + ((size_t)b*16 + ch)*1024 + ky*32 + kx;
        #pragma unroll
        for (int i=0;i<8;i++) v[i] = src[i];
    } else {
        #pragma unroll
        for (int i=0;i<8;i++) v[i] = 0;
    }
    __builtin_memcpy(out + (size_t)g*8, v, 16);
}

__global__ __launch_bounds__(256) void atab2F_kernel(const float* __restrict__ bbw,
                                                     ushort* __restrict__ out)
{
    int g = blockIdx.x*256 + threadIdx.x;      // 4*39*2*64 = 19,968
    int lane = g & 63, half = (g >> 6) & 1;
    int rest = g >> 7;
    int kyp = rest % 39;
    int c = rest / 39;
    int r = lane & 31, hi = lane >> 5;
    int dyA = r >> 2, mA = r & 3;
    int ch = mA*4 + c, ky = kyp - dyA, kx = 16*half + 8*hi;
    ushort v[8];
    if (ky >= 0 && ky < 32) {
        const float* src = bbw + (size_t)ch*1024 + ky*32 + kx;
        #pragma unroll
        for (int i=0;i<8;i++) { bf16 t = f2b(src[i]); v[i] = *(ushort*)&t; }
    } else {
        #pragma unroll
        for (int i=0;i<8;i++) v[i] = 0;
    }
    __builtin_memcpy(out + (size_t)g*8, v, 16);
}

// ================= paired-tile conv: two M=32 tiles share every B fragment =================
// Block 256 thr = 4 waves covering all 384 cols (wave w -> cols [96w,96w+96)).
// Block covers 16 output rows: T1 = yv+0..7, T2 = yv+8..15. Staged window = 47 rows.
// Per staged row r: T1 uses A[r] (r<=38), T2 uses A[r-8] (r>=8) with the SAME 24 B words.
// LDS row: copy0 words 0..207, copy1 words 208..415 (bank-shift 16). 47*416*4 = 78,208 B.
#define G_LOADX4(dst, addr, OFF) \
    asm volatile("global_load_dwordx4 %0, %1, off offset:" OFF : "=v"(dst) : "v"(addr))

#define VMWAIT(N) do { asm volatile("s_waitcnt vmcnt(" N ")" ::: "memory"); \
                       __builtin_amdgcn_sched_barrier(0); } while (0)

#define ISSUE_A(A0_, A1_, ap_, e_)                                   \
{                                                                    \
    const ushort* p_ = (ap_) + (unsigned)(e_)*1024u;                 \
    G_LOADX4(A0_, p_, "0");                                          \
    G_LOADX4(A1_, p_, "1024");                                       \
}

#define READB24(r_)                                                          \
    const uint* rp_ = swl + (unsigned)(r_)*416u;                             \
    uint B00=rp_[0], B01=rp_[1], B02=rp_[2], B03=rp_[3];                     \
    uint B10=rp_[8], B11=rp_[9], B12=rp_[10],B13=rp_[11];                    \
    uint B20=rp_[16],B21=rp_[17],B22=rp_[18],B23=rp_[19];                    \
    uint B30=rp_[24],B31=rp_[25],B32=rp_[26],B33=rp_[27];                    \
    uint B40=rp_[32],B41=rp_[33],B42=rp_[34],B43=rp_[35];                    \
    uint B50=rp_[40],B51=rp_[41],B52=rp_[42],B53=rp_[43];

#define MM(acc_, A_, w0,w1,w2,w3) \
    acc_ = __builtin_amdgcn_mfma_f32_32x32x16_bf16(A_, mk8(w0,w1,w2,w3), acc_, 0,0,0)

#define STEP1(r_, A0_, A1_, WN) {                                            \
    READB24(r_); VMWAIT(WN);                                                 \
    MM(q0, A0_, B00,B01,B02,B03); MM(q0, A1_, B10,B11,B12,B13);              \
    MM(q1, A0_, B20,B21,B22,B23); MM(q1, A1_, B30,B31,B32,B33);              \
    MM(q2, A0_, B40,B41,B42,B43); MM(q2, A1_, B50,B51,B52,B53); }

#define STEP2(r_, C0_, C1_, WN) {                                            \
    READB24(r_); VMWAIT(WN);                                                 \
    MM(u0, C0_, B00,B01,B02,B03); MM(u0, C1_, B10,B11,B12,B13);              \
    MM(u1, C0_, B20,B21,B22,B23); MM(u1, C1_, B30,B31,B32,B33);              \
    MM(u2, C0_, B40,B41,B42,B43); MM(u2, C1_, B50,B51,B52,B53); }

#define STEP12(r_, A0_, A1_, C0_, C1_, WN) {                                 \
    READB24(r_); VMWAIT(WN);                                                 \
    MM(q0, A0_, B00,B01,B02,B03); MM(u0, C0_, B00,B01,B02,B03);              \
    MM(q0, A1_, B10,B11,B12,B13); MM(u0, C1_, B10,B11,B12,B13);              \
    MM(q1, A0_, B20,B21,B22,B23); MM(u1, C0_, B20,B21,B22,B23);              \
    MM(q1, A1_, B30,B31,B32,B33); MM(u1, C1_, B30,B31,B32,B33);              \
    MM(q2, A0_, B40,B41,B42,B43); MM(u2, C0_, B40,B41,B42,B43);              \
    MM(q2, A1_, B50,B51,B52,B53); MM(u2, C1_, B50,B51,B52,B53); }

template<bool PER_B, bool OUT_BF16, bool ADD_BIAS>
__global__ __launch_bounds__(256) void conv32_pair(const ushort* __restrict__ in,
                                                   const ushort* __restrict__ atabF,
                                                   const float* __restrict__ bias,
                                                   void* __restrict__ outp)
{
    __shared__ uint sbuf[47*416];

    // XCD-chunk swizzle (736 % 8 == 0)
    int d = blockIdx.x;
    int chunkg = (int)gridDim.x >> 3;
    int L = (d & 7) * chunkg + (d >> 3);
    int b = L / 23, yb = L % 23;
    int yv = yb * 16;

    int tid = threadIdx.x;
    int l = tid & 63, w = tid >> 6;
    int xs = w * 96;
    int hi = l >> 5;

    int s = xs + (l & 31) + 8*hi;
    int p = s & 1;
    const uint* swl = sbuf + (unsigned)(p*208 + ((s - p) >> 1));

    f32x16 q0, q1, q2, u0, u1, u2;
    #pragma unroll
    for (int i = 0; i < 16; i++) { q0[i]=0.f; q1[i]=0.f; q2[i]=0.f; u0[i]=0.f; u1[i]=0.f; u2[i]=0.f; }

    unsigned chbase0 = (unsigned)b*589824u + (unsigned)yv*384u;

    for (int c = 0; c < 4; ++c) {
        if (c) __syncthreads();
        // ---- stage channel c: rows yv..yv+46, 416 el, 2 parity copies ----
        unsigned chb = chbase0 + (unsigned)c*147456u;
        for (int qq = tid; qq < 2444; qq += 256) {     // 47 rows * 52 chunks of 8 el
            int row = qq / 52, k = qq - row*52;
            unsigned gi = chb + (unsigned)row*384u + (unsigned)k*8u;
            if (gi > TOT_ELEMS - 16u) gi = TOT_ELEMS - 16u;
            const uint* gp = (const uint*)(in + gi);   // 16B aligned
            uint d0 = gp[0], d1 = gp[1], d2 = gp[2], d3 = gp[3], d4 = gp[4];
            unsigned widx = (unsigned)row*416u + (unsigned)k*4u;
            uint4* w0 = (uint4*)&sbuf[widx];
            uint4* w1 = (uint4*)&sbuf[widx + 208u];
            *w0 = make_uint4(d0, d1, d2, d3);
            *w1 = make_uint4(ab2(d1,d0), ab2(d2,d1), ab2(d3,d2), ab2(d4,d3));
        }
        __syncthreads();

        const ushort* ap1 = atabF + (size_t)((PER_B ? (b*4 + c) : c) * 39) * 1024 + l*8;
        short8_t xA0, xA1, yA0, yA1;      // T1 A pipeline
        short8_t x20, x21, y20, y21;      // T2 A pipeline

        // ---- P1: rows 0..7, T1 only ----
        ISSUE_A(xA0, xA1, ap1, 0);
        ISSUE_A(yA0, yA1, ap1, 1);  STEP1(0, xA0, xA1, "2");
        ISSUE_A(xA0, xA1, ap1, 2);  STEP1(1, yA0, yA1, "2");
        ISSUE_A(yA0, yA1, ap1, 3);  STEP1(2, xA0, xA1, "2");
        ISSUE_A(xA0, xA1, ap1, 4);  STEP1(3, yA0, yA1, "2");
        ISSUE_A(yA0, yA1, ap1, 5);  STEP1(4, xA0, xA1, "2");
        ISSUE_A(xA0, xA1, ap1, 6);  STEP1(5, yA0, yA1, "2");
        ISSUE_A(yA0, yA1, ap1, 7);  STEP1(6, xA0, xA1, "2");
        ISSUE_A(xA0, xA1, ap1, 8);
        ISSUE_A(x20, x21, ap1, 0);  STEP1(7, yA0, yA1, "4");

        // ---- P2: rows 8..38, both tiles (T1 entry r, T2 entry r-8) ----
        #pragma unroll 1
        for (int t = 0; t < 15; ++t) {
            int r = 8 + 2*t;
            ISSUE_A(yA0, yA1, ap1, r+1); ISSUE_A(y20, y21, ap1, r-7);
            STEP12(r,   xA0, xA1, x20, x21, "4");
            ISSUE_A(xA0, xA1, ap1, r+2); ISSUE_A(x20, x21, ap1, r-6);
            STEP12(r+1, yA0, yA1, y20, y21, "4");
        }
        ISSUE_A(y20, y21, ap1, 31);
        STEP12(38, xA0, xA1, x20, x21, "2");

        // ---- P3: rows 39..46, T2 only (entries 31..38) ----
        ISSUE_A(x20, x21, ap1, 32);  STEP2(39, y20, y21, "2");
        ISSUE_A(y20, y21, ap1, 33);  STEP2(40, x20, x21, "2");
        ISSUE_A(x20, x21, ap1, 34);  STEP2(41, y20, y21, "2");
        ISSUE_A(y20, y21, ap1, 35);  STEP2(42, x20, x21, "2");
        ISSUE_A(x20, x21, ap1, 36);  STEP2(43, y20, y21, "2");
        ISSUE_A(y20, y21, ap1, 37);  STEP2(44, x20, x21, "2");
        ISSUE_A(x20, x21, ap1, 38);  STEP2(45, y20, y21, "2");
        STEP2(46, x20, x21, "0");
    }

    float bv0 = 0.f, bv1 = 0.f, bv2 = 0.f, bv3 = 0.f;
    if (ADD_BIAS) { bv0 = bias[0]; bv1 = bias[1]; bv2 = bias[2]; bv3 = bias[3]; }

    #pragma unroll
    for (int j = 0; j < 3; j++) {
        int ox = xs + 32*j + (l & 31);
        if (ox > 352) continue;
        int px = ox + 15;
        #pragma unroll
        for (int rg = 0; rg < 16; rg++) {
            int m  = rg & 3;
            int dy = 2*(rg >> 2) + hi;
            float v1 = (j == 0 ? q0[rg] : (j == 1 ? q1[rg] : q2[rg]));
            float v2 = (j == 0 ? u0[rg] : (j == 1 ? u1[rg] : u2[rg]));
            float bb = (m == 0 ? bv0 : m == 1 ? bv1 : m == 2 ? bv2 : bv3);
            int oy1 = yv + dy;
            if (oy1 <= 352) {
                size_t o = ((size_t)(b*4 + m))*HW + (size_t)(oy1 + 15)*HH + px;
                float v = v1 + (ADD_BIAS ? bb : 0.f);
                if constexpr (OUT_BF16) ((bf16*)outp)[o] = f2b(v);
                else                    ((float*)outp)[o] = v;
            }
            int oy2 = yv + 8 + dy;
            if (oy2 <= 352) {
                size_t o = ((size_t)(b*4 + m))*HW + (size_t)(oy2 + 15)*HH + px;
                float v = v2 + (ADD_BIAS ? bb : 0.f);
                if constexpr (OUT_BF16) ((bf16*)outp)[o] = f2b(v);
                else                    ((float*)outp)[o] = v;
            }
        }
    }
}

extern "C" void kernel_launch(void* const* d_in, const int* in_sizes, int n_in,
                              void* d_out, int out_size, void* d_ws, size_t ws_size,
                              hipStream_t stream)
{
    const float* inputs = (const float*)d_in[0];
    const float* fm     = (const float*)d_in[1];
    const float* meta   = (const float*)d_in[2];
    const float* mcw    = (const float*)d_in[3];
    const float* mcb    = (const float*)d_in[4];
    const float* mlw    = (const float*)d_in[5];
    const float* mlb    = (const float*)d_in[6];
    const float* icw    = (const float*)d_in[7];
    const float* icb    = (const float*)d_in[8];
    const float* bbw    = (const float*)d_in[9];
    const float* bbb    = (const float*)d_in[10];

    // workspace layout (bytes):
    //   ci     bf16 [32,4,384,384]      @ 0           37,748,736
    //   mapped bf16 [32,4,384,384]      @ 37,748,736  37,748,736
    //   cf     f32  [32,16,1024]        @ 75,497,472   2,097,152
    //   wts    bf16 [32,16,1024]        @ 77,594,624   1,048,576
    //   atab1F bf16 [32,4,39,2,64,8]    @ 78,643,200  10,223,616
    //   atab2F bf16 [4,39,2,64,8]       @ 88,866,816     319,488
    char* ws = (char*)d_ws;
    bf16*   ci     = (bf16*) ws;
    bf16*   mapped = (bf16*)(ws + 37748736);
    float*  cf     = (float*)(ws + 75497472);
    bf16*   wts    = (bf16*)(ws + 77594624);
    ushort* atab1F = (ushort*)(ws + 78643200);
    ushort* atab2F = (ushort*)(ws + 88866816);

    ci_kernel<<<18432, 256, 0, stream>>>(inputs, icw, icb, ci);
    convfeats_kernel<<<128, 256, 0, stream>>>(fm, mcw, mcb, cf);
    wts_kernel<<<512, 256, 0, stream>>>(meta, mlw, mlb, cf, wts);
    atab1F_kernel<<<2496, 256, 0, stream>>>((const ushort*)wts, atab1F);
    atab2F_kernel<<<78, 256, 0, stream>>>(bbw, atab2F);

    hipMemsetAsync(mapped, 0, 37748736, stream);
    conv32_pair<true, true, false><<<736, 256, 0, stream>>>(
        (const ushort*)ci, atab1F, nullptr, mapped);

    hipMemsetAsync(d_out, 0, (size_t)out_size * 4, stream);
    conv32_pair<false, false, true><<<736, 256, 0, stream>>>(
        (const ushort*)mapped, atab2F, bbb, d_out);
}

// Round 9
// 447.784 us; speedup vs baseline: 22.3870x; 1.0171x over previous
//
#include <hip/hip_runtime.h>
#include <hip/hip_bf16.h>

typedef __hip_bfloat16 bf16;
typedef __attribute__((ext_vector_type(8))) short short8_t;
typedef __attribute__((ext_vector_type(16))) float f32x16;

#define HH 384
#define HW (384*384)
#define TOT_ELEMS (32u*4u*147456u)

__device__ inline float b2f(bf16 v){ return __bfloat162float(v); }
__device__ inline bf16  f2b(float v){ return __float2bfloat16(v); }
__device__ inline float sigm(float x){ return 1.f/(1.f+__expf(-x)); }

__device__ inline short8_t mk8(uint a, uint b, uint c, uint d){
    union { uint u[4]; short8_t s; } t;
    t.u[0]=a; t.u[1]=b; t.u[2]=c; t.u[3]=d; return t.s;
}
__device__ inline uint ab2(uint h, uint l){ return __builtin_amdgcn_alignbyte(h, l, 2); }

// ---------------- K1: ci = sigmoid(pad1(conv3x3(inputs)+ic_b)), border = 0.5 ----------------
__global__ __launch_bounds__(256) void ci_kernel(const float* __restrict__ in,
                                                 const float* __restrict__ icw,
                                                 const float* __restrict__ icb,
                                                 bf16* __restrict__ ci)
{
    __shared__ float sw[108];
    __shared__ float sb[4];
    int tid = threadIdx.x;
    if (tid < 108) sw[tid] = icw[tid];
    if (tid < 4)   sb[tid] = icb[tid];
    __syncthreads();
    size_t idx = (size_t)blockIdx.x * 256 + tid;
    int x = (int)(idx % HH);
    int y = (int)((idx / HH) % HH);
    int b = (int)(idx / ((size_t)HH * HH));
    float v[4];
    if (y > 0 && y < HH-1 && x > 0 && x < HH-1) {
        float a0 = sb[0], a1 = sb[1], a2 = sb[2], a3 = sb[3];
        for (int ic = 0; ic < 3; ic++) {
            #pragma unroll
            for (int dy = 0; dy < 3; dy++) {
                #pragma unroll
                for (int dx = 0; dx < 3; dx++) {
                    float iv = in[((size_t)(b*3+ic)*HH + (y-1+dy))*HH + (x-1+dx)];
                    a0 = fmaf(iv, sw[0*27 + ic*9 + dy*3 + dx], a0);
                    a1 = fmaf(iv, sw[1*27 + ic*9 + dy*3 + dx], a1);
                    a2 = fmaf(iv, sw[2*27 + ic*9 + dy*3 + dx], a2);
                    a3 = fmaf(iv, sw[3*27 + ic*9 + dy*3 + dx], a3);
                }
            }
        }
        v[0]=sigm(a0); v[1]=sigm(a1); v[2]=sigm(a2); v[3]=sigm(a3);
    } else {
        v[0]=v[1]=v[2]=v[3]=0.5f;
    }
    #pragma unroll
    for (int o = 0; o < 4; o++)
        ci[((size_t)(b*4+o)*HH + y)*HH + x] = f2b(v[o]);
}

// ---------------- K2a: conv_feats ----------------
__global__ __launch_bounds__(256) void convfeats_kernel(const float* __restrict__ fm,
                                                        const float* __restrict__ mcw,
                                                        const float* __restrict__ mcb,
                                                        float* __restrict__ cf)
{
    __shared__ float sw[256*16];   // [c][k]
    int tid = threadIdx.x;
    int b = blockIdx.x >> 2, chunk = blockIdx.x & 3;
    for (int i = tid; i < 4096; i += 256) {
        int k = i / 256, c = i % 256;
        sw[c*16 + k] = mcw[k*256 + c];
    }
    __syncthreads();
    int hw = chunk*256 + tid;
    float acc[16];
    #pragma unroll
    for (int k = 0; k < 16; k++) acc[k] = mcb[k];
    const float* f = fm + (size_t)b*256*1024 + hw;
    for (int c = 0; c < 256; c++) {
        float v = f[(size_t)c*1024];
        const float4* wp = (const float4*)(sw + c*16);
        #pragma unroll
        for (int q = 0; q < 4; q++) {
            float4 t = wp[q];
            acc[q*4+0] = fmaf(v, t.x, acc[q*4+0]);
            acc[q*4+1] = fmaf(v, t.y, acc[q*4+1]);
            acc[q*4+2] = fmaf(v, t.z, acc[q*4+2]);
            acc[q*4+3] = fmaf(v, t.w, acc[q*4+3]);
        }
    }
    #pragma unroll
    for (int k = 0; k < 16; k++)
        cf[(size_t)b*16384 + k*1024 + hw] = acc[k];
}

// -------- K2c: wts = sigmoid((cf)@(meta@mlW.T+mlb)) -> bf16 [b][16][1024] --------
__global__ __launch_bounds__(256) void wts_kernel(const float* __restrict__ meta,
                                                  const float* __restrict__ mlw,
                                                  const float* __restrict__ mlb,
                                                  const float* __restrict__ cf,
                                                  bf16* __restrict__ wout)
{
    __shared__ float sm[64];
    __shared__ float sA[1024];
    __shared__ float sB[1024];
    int tid = threadIdx.x;
    int b = blockIdx.x >> 4, k = blockIdx.x & 15;
    if (tid < 64) sm[tid] = meta[(size_t)b*16*64 + k*64 + tid];
    #pragma unroll
    for (int q = 0; q < 4; q++)
        sA[q*256 + tid] = cf[(size_t)b*16384 + k*1024 + q*256 + tid];
    __syncthreads();
    #pragma unroll
    for (int q = 0; q < 4; q++) {
        int hw = q*256 + tid;
        const float4* wr = (const float4*)(mlw + (size_t)hw*64);
        float a = mlb[hw];
        #pragma unroll
        for (int d4 = 0; d4 < 16; d4++) {
            float4 t = wr[d4];
            a = fmaf(t.x, sm[d4*4+0], a);
            a = fmaf(t.y, sm[d4*4+1], a);
            a = fmaf(t.z, sm[d4*4+2], a);
            a = fmaf(t.w, sm[d4*4+3], a);
        }
        sB[hw] = a;
    }
    __syncthreads();
    #pragma unroll
    for (int q = 0; q < 4; q++) {
        int il = q*256 + tid;
        int i = il >> 5, l = il & 31;
        float a = 0.f;
        #pragma unroll
        for (int j = 0; j < 32; j++)
            a = fmaf(sA[i*32 + j], sB[j*32 + l], a);
        wout[(size_t)b*16384 + k*1024 + il] = f2b(sigm(a));
    }
}

// -------- A-fragment tables in MFMA lane order: [b][c][kyp][half][lane][8] --------
__global__ __launch_bounds__(256) void atab1F_kernel(const ushort* __restrict__ wts,
                                                     ushort* __restrict__ out)
{
    int g = blockIdx.x*256 + threadIdx.x;      // 32*4*39*2*64 = 638,976
    int lane = g & 63, half = (g >> 6) & 1;
    int rest = g >> 7;
    int kyp = rest % 39; int rest2 = rest / 39;
    int c = rest2 & 3, b = rest2 >> 2;
    int r = lane & 31, hi = lane >> 5;
    int dyA = r >> 2, mA = r & 3;
    int ch = mA*4 + c, ky = kyp - dyA, kx = 16*half + 8*hi;
    ushort v[8];
    if (ky >= 0 && ky < 32) {
        const ushort* src = wts + ((size_t)b*16 + ch)*1024 + ky*32 + kx;
        #pragma unroll
        for (int i=0;i<8;i++) v[i] = src[i];
    } else {
        #pragma unroll
        for (int i=0;i<8;i++) v[i] = 0;
    }
    __builtin_memcpy(out + (size_t)g*8, v, 16);
}

__global__ __launch_bounds__(256) void atab2F_kernel(const float* __restrict__ bbw,
                                                     ushort* __restrict__ out)
{
    int g = blockIdx.x*256 + threadIdx.x;      // 4*39*2*64 = 19,968
    int lane = g & 63, half = (g >> 6) & 1;
    int rest = g >> 7;
    int kyp = rest % 39;
    int c = rest / 39;
    int r = lane & 31, hi = lane >> 5;
    int dyA = r >> 2, mA = r & 3;
    int ch = mA*4 + c, ky = kyp - dyA, kx = 16*half + 8*hi;
    ushort v[8];
    if (ky >= 0 && ky < 32) {
        const float* src = bbw + (size_t)ch*1024 + ky*32 + kx;
        #pragma unroll
        for (int i=0;i<8;i++) { bf16 t = f2b(src[i]); v[i] = *(ushort*)&t; }
    } else {
        #pragma unroll
        for (int i=0;i<8;i++) v[i] = 0;
    }
    __builtin_memcpy(out + (size_t)g*8, v, 16);
}

// ================= quad-tile conv: 4 waves = {x-half} x {row-group}, 2 blocks/CU =================
// Block covers 32 output rows x 192 cols. Wave w: xs=(w&1)*96 (local), rowoff=(w>>1)*16.
// Each wave runs the paired-tile body (T1 rows rowoff+0..7, T2 rowoff+8..15) over 47 staged
// rows (local rowoff..rowoff+46). Staged window 63 rows x 224 words (copy0 112 | copy1 112,
// +112 = bank-shift 16) = 56,448 B -> 2 blocks/CU. All ds offsets <= 55,552 (16-bit imm OK).
#define G_LOADX4(dst, addr, OFF) \
    asm volatile("global_load_dwordx4 %0, %1, off offset:" OFF : "=v"(dst) : "v"(addr))

#define VMWAIT(N) do { asm volatile("s_waitcnt vmcnt(" N ")" ::: "memory"); \
                       __builtin_amdgcn_sched_barrier(0); } while (0)

#define ISSUE_A(A0_, A1_, ap_, e_)                                   \
{                                                                    \
    const ushort* p_ = (ap_) + (unsigned)(e_)*1024u;                 \
    G_LOADX4(A0_, p_, "0");                                          \
    G_LOADX4(A1_, p_, "1024");                                       \
}

#define READB24(r_)                                                          \
    const uint* rp_ = swl + (unsigned)(r_)*224u;                             \
    uint B00=rp_[0], B01=rp_[1], B02=rp_[2], B03=rp_[3];                     \
    uint B10=rp_[8], B11=rp_[9], B12=rp_[10],B13=rp_[11];                    \
    uint B20=rp_[16],B21=rp_[17],B22=rp_[18],B23=rp_[19];                    \
    uint B30=rp_[24],B31=rp_[25],B32=rp_[26],B33=rp_[27];                    \
    uint B40=rp_[32],B41=rp_[33],B42=rp_[34],B43=rp_[35];                    \
    uint B50=rp_[40],B51=rp_[41],B52=rp_[42],B53=rp_[43];

#define MM(acc_, A_, w0,w1,w2,w3) \
    acc_ = __builtin_amdgcn_mfma_f32_32x32x16_bf16(A_, mk8(w0,w1,w2,w3), acc_, 0,0,0)

#define STEP1(r_, A0_, A1_, WN) {                                            \
    READB24(r_); VMWAIT(WN);                                                 \
    MM(q0, A0_, B00,B01,B02,B03); MM(q0, A1_, B10,B11,B12,B13);              \
    MM(q1, A0_, B20,B21,B22,B23); MM(q1, A1_, B30,B31,B32,B33);              \
    MM(q2, A0_, B40,B41,B42,B43); MM(q2, A1_, B50,B51,B52,B53); }

#define STEP2(r_, C0_, C1_, WN) {                                            \
    READB24(r_); VMWAIT(WN);                                                 \
    MM(u0, C0_, B00,B01,B02,B03); MM(u0, C1_, B10,B11,B12,B13);              \
    MM(u1, C0_, B20,B21,B22,B23); MM(u1, C1_, B30,B31,B32,B33);              \
    MM(u2, C0_, B40,B41,B42,B43); MM(u2, C1_, B50,B51,B52,B53); }

#define STEP12(r_, A0_, A1_, C0_, C1_, WN) {                                 \
    READB24(r_); VMWAIT(WN);                                                 \
    MM(q0, A0_, B00,B01,B02,B03); MM(u0, C0_, B00,B01,B02,B03);              \
    MM(q0, A1_, B10,B11,B12,B13); MM(u0, C1_, B10,B11,B12,B13);              \
    MM(q1, A0_, B20,B21,B22,B23); MM(u1, C0_, B20,B21,B22,B23);              \
    MM(q1, A1_, B30,B31,B32,B33); MM(u1, C1_, B30,B31,B32,B33);              \
    MM(q2, A0_, B40,B41,B42,B43); MM(u2, C0_, B40,B41,B42,B43);              \
    MM(q2, A1_, B50,B51,B52,B53); MM(u2, C1_, B50,B51,B52,B53); }

template<bool PER_B, bool OUT_BF16, bool ADD_BIAS>
__global__ __launch_bounds__(256) void conv32_quad(const ushort* __restrict__ in,
                                                   const ushort* __restrict__ atabF,
                                                   const float* __restrict__ bias,
                                                   void* __restrict__ outp)
{
    __shared__ uint sbuf[63*224];   // 56,448 B

    // XCD-chunk swizzle (768 % 8 == 0)
    int d = blockIdx.x;
    int chunkg = (int)gridDim.x >> 3;
    int L = (d & 7) * chunkg + (d >> 3);
    int b = L / 24; int rem = L % 24;
    int yb = rem >> 1, xb = rem & 1;
    int yv = yb * 32;
    int x0 = xb * 192;

    int tid = threadIdx.x;
    int l = tid & 63, w = tid >> 6;
    int rowoff = (w >> 1) * 16;        // row-group 0 / 16
    int xs = (w & 1) * 96;             // local x start within 192-col block
    int hi = l >> 5;

    int s = xs + (l & 31) + 8*hi;      // local start element (0..135)
    int p = s & 1;
    const uint* swl = sbuf + (unsigned)(rowoff*224) + (unsigned)(p*112 + ((s - p) >> 1));

    f32x16 q0, q1, q2, u0, u1, u2;
    #pragma unroll
    for (int i = 0; i < 16; i++) { q0[i]=0.f; q1[i]=0.f; q2[i]=0.f; u0[i]=0.f; u1[i]=0.f; u2[i]=0.f; }

    unsigned chbase0 = (unsigned)b*589824u + (unsigned)yv*384u + (unsigned)x0;

    for (int c = 0; c < 4; ++c) {
        if (c) __syncthreads();
        // ---- stage channel c: local rows 0..62 (image rows yv..yv+62), 224 elems + parity copy ----
        unsigned chb = chbase0 + (unsigned)c*147456u;
        for (int qq = tid; qq < 1764; qq += 256) {     // 63 rows * 28 chunks of 8 el
            int row = qq / 28, k = qq - row*28;
            unsigned gi = chb + (unsigned)row*384u + (unsigned)k*8u;
            if (gi > TOT_ELEMS - 16u) gi = TOT_ELEMS - 16u;
            const uint* gp = (const uint*)(in + gi);   // 16B aligned
            uint d0 = gp[0], d1 = gp[1], d2 = gp[2], d3 = gp[3], d4 = gp[4];
            unsigned widx = (unsigned)row*224u + (unsigned)k*4u;
            uint4* w0 = (uint4*)&sbuf[widx];
            uint4* w1 = (uint4*)&sbuf[widx + 112u];
            *w0 = make_uint4(d0, d1, d2, d3);
            *w1 = make_uint4(ab2(d1,d0), ab2(d2,d1), ab2(d3,d2), ab2(d4,d3));
        }
        __syncthreads();

        const ushort* ap1 = atabF + (size_t)((PER_B ? (b*4 + c) : c) * 39) * 1024 + l*8;
        short8_t xA0, xA1, yA0, yA1;      // T1 A pipeline
        short8_t x20, x21, y20, y21;      // T2 A pipeline

        // ---- P1: local rows 0..7, T1 only ----
        ISSUE_A(xA0, xA1, ap1, 0);
        ISSUE_A(yA0, yA1, ap1, 1);  STEP1(0, xA0, xA1, "2");
        ISSUE_A(xA0, xA1, ap1, 2);  STEP1(1, yA0, yA1, "2");
        ISSUE_A(yA0, yA1, ap1, 3);  STEP1(2, xA0, xA1, "2");
        ISSUE_A(xA0, xA1, ap1, 4);  STEP1(3, yA0, yA1, "2");
        ISSUE_A(yA0, yA1, ap1, 5);  STEP1(4, xA0, xA1, "2");
        ISSUE_A(xA0, xA1, ap1, 6);  STEP1(5, yA0, yA1, "2");
        ISSUE_A(yA0, yA1, ap1, 7);  STEP1(6, xA0, xA1, "2");
        ISSUE_A(xA0, xA1, ap1, 8);
        ISSUE_A(x20, x21, ap1, 0);  STEP1(7, yA0, yA1, "4");

        // ---- P2: local rows 8..38, both tiles (T1 entry r, T2 entry r-8) ----
        #pragma unroll 1
        for (int t = 0; t < 15; ++t) {
            int r = 8 + 2*t;
            ISSUE_A(yA0, yA1, ap1, r+1); ISSUE_A(y20, y21, ap1, r-7);
            STEP12(r,   xA0, xA1, x20, x21, "4");
            ISSUE_A(xA0, xA1, ap1, r+2); ISSUE_A(x20, x21, ap1, r-6);
            STEP12(r+1, yA0, yA1, y20, y21, "4");
        }
        ISSUE_A(y20, y21, ap1, 31);
        STEP12(38, xA0, xA1, x20, x21, "2");

        // ---- P3: local rows 39..46, T2 only (entries 31..38) ----
        ISSUE_A(x20, x21, ap1, 32);  STEP2(39, y20, y21, "2");
        ISSUE_A(y20, y21, ap1, 33);  STEP2(40, x20, x21, "2");
        ISSUE_A(x20, x21, ap1, 34);  STEP2(41, y20, y21, "2");
        ISSUE_A(y20, y21, ap1, 35);  STEP2(42, x20, x21, "2");
        ISSUE_A(x20, x21, ap1, 36);  STEP2(43, y20, y21, "2");
        ISSUE_A(y20, y21, ap1, 37);  STEP2(44, x20, x21, "2");
        ISSUE_A(x20, x21, ap1, 38);  STEP2(45, y20, y21, "2");
        STEP2(46, x20, x21, "0");
    }

    float bv0 = 0.f, bv1 = 0.f, bv2 = 0.f, bv3 = 0.f;
    if (ADD_BIAS) { bv0 = bias[0]; bv1 = bias[1]; bv2 = bias[2]; bv3 = bias[3]; }

    #pragma unroll
    for (int j = 0; j < 3; j++) {
        int ox = x0 + xs + 32*j + (l & 31);
        if (ox > 352) continue;
        int px = ox + 15;
        #pragma unroll
        for (int rg = 0; rg < 16; rg++) {
            int m  = rg & 3;
            int dy = 2*(rg >> 2) + hi;
            float v1 = (j == 0 ? q0[rg] : (j == 1 ? q1[rg] : q2[rg]));
            float v2 = (j == 0 ? u0[rg] : (j == 1 ? u1[rg] : u2[rg]));
            float bb = (m == 0 ? bv0 : m == 1 ? bv1 : m == 2 ? bv2 : bv3);
            int oy1 = yv + rowoff + dy;
            if (oy1 <= 352) {
                size_t o = ((size_t)(b*4 + m))*HW + (size_t)(oy1 + 15)*HH + px;
                float v = v1 + (ADD_BIAS ? bb : 0.f);
                if constexpr (OUT_BF16) ((bf16*)outp)[o] = f2b(v);
                else                    ((float*)outp)[o] = v;
            }
            int oy2 = yv + rowoff + 8 + dy;
            if (oy2 <= 352) {
                size_t o = ((size_t)(b*4 + m))*HW + (size_t)(oy2 + 15)*HH + px;
                float v = v2 + (ADD_BIAS ? bb : 0.f);
                if constexpr (OUT_BF16) ((bf16*)outp)[o] = f2b(v);
                else                    ((float*)outp)[o] = v;
            }
        }
    }
}

extern "C" void kernel_launch(void* const* d_in, const int* in_sizes, int n_in,
                              void* d_out, int out_size, void* d_ws, size_t ws_size,
                              hipStream_t stream)
{
    const float* inputs = (const float*)d_in[0];
    const float* fm     = (const float*)d_in[1];
    const float* meta   = (const float*)d_in[2];
    const float* mcw    = (const float*)d_in[3];
    const float* mcb    = (const float*)d_in[4];
    const float* mlw    = (const float*)d_in[5];
    const float* mlb    = (const float*)d_in[6];
    const float* icw    = (const float*)d_in[7];
    const float* icb    = (const float*)d_in[8];
    const float* bbw    = (const float*)d_in[9];
    const float* bbb    = (const float*)d_in[10];

    // workspace layout (bytes):
    //   ci     bf16 [32,4,384,384]      @ 0           37,748,736
    //   mapped bf16 [32,4,384,384]      @ 37,748,736  37,748,736
    //   cf     f32  [32,16,1024]        @ 75,497,472   2,097,152
    //   wts    bf16 [32,16,1024]        @ 77,594,624   1,048,576
    //   atab1F bf16 [32,4,39,2,64,8]    @ 78,643,200  10,223,616
    //   atab2F bf16 [4,39,2,64,8]       @ 88,866,816     319,488
    char* ws = (char*)d_ws;
    bf16*   ci     = (bf16*) ws;
    bf16*   mapped = (bf16*)(ws + 37748736);
    float*  cf     = (float*)(ws + 75497472);
    bf16*   wts    = (bf16*)(ws + 77594624);
    ushort* atab1F = (ushort*)(ws + 78643200);
    ushort* atab2F = (ushort*)(ws + 88866816);

    ci_kernel<<<18432, 256, 0, stream>>>(inputs, icw, icb, ci);
    convfeats_kernel<<<128, 256, 0, stream>>>(fm, mcw, mcb, cf);
    wts_kernel<<<512, 256, 0, stream>>>(meta, mlw, mlb, cf, wts);
    atab1F_kernel<<<2496, 256, 0, stream>>>((const ushort*)wts, atab1F);
    atab2F_kernel<<<78, 256, 0, stream>>>(bbw, atab2F);

    hipMemsetAsync(mapped, 0, 37748736, stream);
    conv32_quad<true, true, false><<<768, 256, 0, stream>>>(
        (const ushort*)ci, atab1F, nullptr, mapped);

    hipMemsetAsync(d_out, 0, (size_t)out_size * 4, stream);
    conv32_quad<false, false, true><<<768, 256, 0, stream>>>(
        (const ushort*)mapped, atab2F, bbb, d_out);
}

// Round 10
// 447.196 us; speedup vs baseline: 22.4165x; 1.0013x over previous
//
#include <hip/hip_runtime.h>
#include <hip/hip_bf16.h>

typedef __hip_bfloat16 bf16;
typedef __attribute__((ext_vector_type(8))) short short8_t;
typedef __attribute__((ext_vector_type(16))) float f32x16;
typedef __attribute__((ext_vector_type(2))) unsigned int uint2v;

#define HH 384
#define HW (384*384)
#define TOT_ELEMS (32u*4u*147456u)

__device__ inline float b2f(bf16 v){ return __bfloat162float(v); }
__device__ inline bf16  f2b(float v){ return __float2bfloat16(v); }
__device__ inline float sigm(float x){ return 1.f/(1.f+__expf(-x)); }

__device__ inline short8_t mk8p(uint2v a, uint2v b){
    union { uint u[4]; short8_t s; } t;
    t.u[0]=a[0]; t.u[1]=a[1]; t.u[2]=b[0]; t.u[3]=b[1]; return t.s;
}
__device__ inline uint ab2(uint h, uint l){ return __builtin_amdgcn_alignbyte(h, l, 2); }

// ---------------- K1: ci = sigmoid(pad1(conv3x3(inputs)+ic_b)), border = 0.5 ----------------
__global__ __launch_bounds__(256) void ci_kernel(const float* __restrict__ in,
                                                 const float* __restrict__ icw,
                                                 const float* __restrict__ icb,
                                                 bf16* __restrict__ ci)
{
    __shared__ float sw[108];
    __shared__ float sb[4];
    int tid = threadIdx.x;
    if (tid < 108) sw[tid] = icw[tid];
    if (tid < 4)   sb[tid] = icb[tid];
    __syncthreads();
    size_t idx = (size_t)blockIdx.x * 256 + tid;
    int x = (int)(idx % HH);
    int y = (int)((idx / HH) % HH);
    int b = (int)(idx / ((size_t)HH * HH));
    float v[4];
    if (y > 0 && y < HH-1 && x > 0 && x < HH-1) {
        float a0 = sb[0], a1 = sb[1], a2 = sb[2], a3 = sb[3];
        for (int ic = 0; ic < 3; ic++) {
            #pragma unroll
            for (int dy = 0; dy < 3; dy++) {
                #pragma unroll
                for (int dx = 0; dx < 3; dx++) {
                    float iv = in[((size_t)(b*3+ic)*HH + (y-1+dy))*HH + (x-1+dx)];
                    a0 = fmaf(iv, sw[0*27 + ic*9 + dy*3 + dx], a0);
                    a1 = fmaf(iv, sw[1*27 + ic*9 + dy*3 + dx], a1);
                    a2 = fmaf(iv, sw[2*27 + ic*9 + dy*3 + dx], a2);
                    a3 = fmaf(iv, sw[3*27 + ic*9 + dy*3 + dx], a3);
                }
            }
        }
        v[0]=sigm(a0); v[1]=sigm(a1); v[2]=sigm(a2); v[3]=sigm(a3);
    } else {
        v[0]=v[1]=v[2]=v[3]=0.5f;
    }
    #pragma unroll
    for (int o = 0; o < 4; o++)
        ci[((size_t)(b*4+o)*HH + y)*HH + x] = f2b(v[o]);
}

// ---------------- K2a: conv_feats ----------------
__global__ __launch_bounds__(256) void convfeats_kernel(const float* __restrict__ fm,
                                                        const float* __restrict__ mcw,
                                                        const float* __restrict__ mcb,
                                                        float* __restrict__ cf)
{
    __shared__ float sw[256*16];   // [c][k]
    int tid = threadIdx.x;
    int b = blockIdx.x >> 2, chunk = blockIdx.x & 3;
    for (int i = tid; i < 4096; i += 256) {
        int k = i / 256, c = i % 256;
        sw[c*16 + k] = mcw[k*256 + c];
    }
    __syncthreads();
    int hw = chunk*256 + tid;
    float acc[16];
    #pragma unroll
    for (int k = 0; k < 16; k++) acc[k] = mcb[k];
    const float* f = fm + (size_t)b*256*1024 + hw;
    for (int c = 0; c < 256; c++) {
        float v = f[(size_t)c*1024];
        const float4* wp = (const float4*)(sw + c*16);
        #pragma unroll
        for (int q = 0; q < 4; q++) {
            float4 t = wp[q];
            acc[q*4+0] = fmaf(v, t.x, acc[q*4+0]);
            acc[q*4+1] = fmaf(v, t.y, acc[q*4+1]);
            acc[q*4+2] = fmaf(v, t.z, acc[q*4+2]);
            acc[q*4+3] = fmaf(v, t.w, acc[q*4+3]);
        }
    }
    #pragma unroll
    for (int k = 0; k < 16; k++)
        cf[(size_t)b*16384 + k*1024 + hw] = acc[k];
}

// -------- K2c: wts = sigmoid((cf)@(meta@mlW.T+mlb)) -> bf16 [b][16][1024] --------
__global__ __launch_bounds__(256) void wts_kernel(const float* __restrict__ meta,
                                                  const float* __restrict__ mlw,
                                                  const float* __restrict__ mlb,
                                                  const float* __restrict__ cf,
                                                  bf16* __restrict__ wout)
{
    __shared__ float sm[64];
    __shared__ float sA[1024];
    __shared__ float sB[1024];
    int tid = threadIdx.x;
    int b = blockIdx.x >> 4, k = blockIdx.x & 15;
    if (tid < 64) sm[tid] = meta[(size_t)b*16*64 + k*64 + tid];
    #pragma unroll
    for (int q = 0; q < 4; q++)
        sA[q*256 + tid] = cf[(size_t)b*16384 + k*1024 + q*256 + tid];
    __syncthreads();
    #pragma unroll
    for (int q = 0; q < 4; q++) {
        int hw = q*256 + tid;
        const float4* wr = (const float4*)(mlw + (size_t)hw*64);
        float a = mlb[hw];
        #pragma unroll
        for (int d4 = 0; d4 < 16; d4++) {
            float4 t = wr[d4];
            a = fmaf(t.x, sm[d4*4+0], a);
            a = fmaf(t.y, sm[d4*4+1], a);
            a = fmaf(t.z, sm[d4*4+2], a);
            a = fmaf(t.w, sm[d4*4+3], a);
        }
        sB[hw] = a;
    }
    __syncthreads();
    #pragma unroll
    for (int q = 0; q < 4; q++) {
        int il = q*256 + tid;
        int i = il >> 5, l = il & 31;
        float a = 0.f;
        #pragma unroll
        for (int j = 0; j < 32; j++)
            a = fmaf(sA[i*32 + j], sB[j*32 + l], a);
        wout[(size_t)b*16384 + k*1024 + il] = f2b(sigm(a));
    }
}

// -------- A-fragment tables in MFMA lane order: [b][c][kyp][half][lane][8] --------
__global__ __launch_bounds__(256) void atab1F_kernel(const ushort* __restrict__ wts,
                                                     ushort* __restrict__ out)
{
    int g = blockIdx.x*256 + threadIdx.x;      // 32*4*39*2*64 = 638,976
    int lane = g & 63, half = (g >> 6) & 1;
    int rest = g >> 7;
    int kyp = rest % 39; int rest2 = rest / 39;
    int c = rest2 & 3, b = rest2 >> 2;
    int r = lane & 31, hi = lane >> 5;
    int dyA = r >> 2, mA = r & 3;
    int ch = mA*4 + c, ky = kyp - dyA, kx = 16*half + 8*hi;
    ushort v[8];
    if (ky >= 0 && ky < 32) {
        const ushort* src = wts + ((size_t)b*16 + ch)*1024 + ky*32 + kx;
        #pragma unroll
        for (int i=0;i<8;i++) v[i] = src[i];
    } else {
        #pragma unroll
        for (int i=0;i<8;i++) v[i] = 0;
    }
    __builtin_memcpy(out + (size_t)g*8, v, 16);
}

__global__ __launch_bounds__(256) void atab2F_kernel(const float* __restrict__ bbw,
                                                     ushort* __restrict__ out)
{
    int g = blockIdx.x*256 + threadIdx.x;      // 4*39*2*64 = 19,968
    int lane = g & 63, half = (g >> 6) & 1;
    int rest = g >> 7;
    int kyp = rest % 39;
    int c = rest / 39;
    int r = lane & 31, hi = lane >> 5;
    int dyA = r >> 2, mA = r & 3;
    int ch = mA*4 + c, ky = kyp - dyA, kx = 16*half + 8*hi;
    ushort v[8];
    if (ky >= 0 && ky < 32) {
        const float* src = bbw + (size_t)ch*1024 + ky*32 + kx;
        #pragma unroll
        for (int i=0;i<8;i++) { bf16 t = f2b(src[i]); v[i] = *(ushort*)&t; }
    } else {
        #pragma unroll
        for (int i=0;i<8;i++) v[i] = 0;
    }
    __builtin_memcpy(out + (size_t)g*8, v, 16);
}

// ================= quad-tile conv, lgkm-pipelined B reads =================
// Block covers 32 output rows x 192 cols. Wave w: xs=(w&1)*96 (local), rowoff=(w>>1)*16.
// Per step: 12 x ds_read2_b32 (next step) -> s_waitcnt vmcnt lgkmcnt(12) -> 12 MFMA (cur).
#define G_LOADX4(dst, addr, OFF) \
    asm volatile("global_load_dwordx4 %0, %1, off offset:" OFF : "=v"(dst) : "v"(addr))

#define ISSUE_A(A0_, A1_, ap_, e_)                                   \
{                                                                    \
    const ushort* p_ = (ap_) + (unsigned)(e_)*1024u;                 \
    G_LOADX4(A0_, p_, "0");                                          \
    G_LOADX4(A1_, p_, "1024");                                       \
}

#define ISSUE_B(S, ADDR)                                                     \
    asm volatile(                                                            \
        "ds_read2_b32 %0, %12 offset0:0 offset1:1\n\t"                       \
        "ds_read2_b32 %1, %12 offset0:2 offset1:3\n\t"                       \
        "ds_read2_b32 %2, %12 offset0:8 offset1:9\n\t"                       \
        "ds_read2_b32 %3, %12 offset0:10 offset1:11\n\t"                     \
        "ds_read2_b32 %4, %12 offset0:16 offset1:17\n\t"                     \
        "ds_read2_b32 %5, %12 offset0:18 offset1:19\n\t"                     \
        "ds_read2_b32 %6, %12 offset0:24 offset1:25\n\t"                     \
        "ds_read2_b32 %7, %12 offset0:26 offset1:27\n\t"                     \
        "ds_read2_b32 %8, %12 offset0:32 offset1:33\n\t"                     \
        "ds_read2_b32 %9, %12 offset0:34 offset1:35\n\t"                     \
        "ds_read2_b32 %10, %12 offset0:40 offset1:41\n\t"                    \
        "ds_read2_b32 %11, %12 offset0:42 offset1:43"                        \
        : "=v"(S[0]), "=v"(S[1]), "=v"(S[2]), "=v"(S[3]), "=v"(S[4]),        \
          "=v"(S[5]), "=v"(S[6]), "=v"(S[7]), "=v"(S[8]), "=v"(S[9]),        \
          "=v"(S[10]), "=v"(S[11])                                           \
        : "v"(ADDR) : "memory")

#define KWAIT(VN, LN) do {                                                      \
    asm volatile("s_waitcnt vmcnt(" VN ") lgkmcnt(" LN ")" ::: "memory");       \
    __builtin_amdgcn_sched_barrier(0); } while (0)

#define MMp(acc_, A_, Pa, Pb) \
    acc_ = __builtin_amdgcn_mfma_f32_32x32x16_bf16(A_, mk8p(Pa, Pb), acc_, 0, 0, 0)

#define STEP1B(S, A0_, A1_, VN, LN) { KWAIT(VN, LN);                          \
    MMp(q0, A0_, S[0], S[1]);  MMp(q0, A1_, S[2], S[3]);                      \
    MMp(q1, A0_, S[4], S[5]);  MMp(q1, A1_, S[6], S[7]);                      \
    MMp(q2, A0_, S[8], S[9]);  MMp(q2, A1_, S[10], S[11]); }

#define STEP2B(S, C0_, C1_, VN, LN) { KWAIT(VN, LN);                          \
    MMp(u0, C0_, S[0], S[1]);  MMp(u0, C1_, S[2], S[3]);                      \
    MMp(u1, C0_, S[4], S[5]);  MMp(u1, C1_, S[6], S[7]);                      \
    MMp(u2, C0_, S[8], S[9]);  MMp(u2, C1_, S[10], S[11]); }

#define STEP12B(S, A0_, A1_, C0_, C1_, VN, LN) { KWAIT(VN, LN);               \
    MMp(q0, A0_, S[0], S[1]);   MMp(u0, C0_, S[0], S[1]);                     \
    MMp(q0, A1_, S[2], S[3]);   MMp(u0, C1_, S[2], S[3]);                     \
    MMp(q1, A0_, S[4], S[5]);   MMp(u1, C0_, S[4], S[5]);                     \
    MMp(q1, A1_, S[6], S[7]);   MMp(u1, C1_, S[6], S[7]);                     \
    MMp(q2, A0_, S[8], S[9]);   MMp(u2, C0_, S[8], S[9]);                     \
    MMp(q2, A1_, S[10], S[11]); MMp(u2, C1_, S[10], S[11]); }

template<bool PER_B, bool OUT_BF16, bool ADD_BIAS>
__global__ __launch_bounds__(256) void conv32_quad(const ushort* __restrict__ in,
                                                   const ushort* __restrict__ atabF,
                                                   const float* __restrict__ bias,
                                                   void* __restrict__ outp)
{
    __shared__ uint sbuf[63*224];   // 56,448 B

    // XCD-chunk swizzle (768 % 8 == 0)
    int d = blockIdx.x;
    int chunkg = (int)gridDim.x >> 3;
    int L = (d & 7) * chunkg + (d >> 3);
    int b = L / 24; int rem = L % 24;
    int yb = rem >> 1, xb = rem & 1;
    int yv = yb * 32;
    int x0 = xb * 192;

    int tid = threadIdx.x;
    int l = tid & 63, w = tid >> 6;
    int rowoff = (w >> 1) * 16;        // row-group 0 / 16
    int xs = (w & 1) * 96;             // local x start within 192-col block
    int hi = l >> 5;

    int s = xs + (l & 31) + 8*hi;      // local start element (0..135)
    int p = s & 1;
    const uint* swl = sbuf + (unsigned)(rowoff*224) + (unsigned)(p*112 + ((s - p) >> 1));
    uint baddr0 = (uint)(size_t)(const void*)swl;   // LDS byte offset (aperture low-32 = 0)

    f32x16 q0, q1, q2, u0, u1, u2;
    #pragma unroll
    for (int i = 0; i < 16; i++) { q0[i]=0.f; q1[i]=0.f; q2[i]=0.f; u0[i]=0.f; u1[i]=0.f; u2[i]=0.f; }

    unsigned chbase0 = (unsigned)b*589824u + (unsigned)yv*384u + (unsigned)x0;

    for (int c = 0; c < 4; ++c) {
        if (c) __syncthreads();
        // ---- stage channel c: local rows 0..62 (image rows yv..yv+62), 224 elems + parity copy ----
        unsigned chb = chbase0 + (unsigned)c*147456u;
        for (int qq = tid; qq < 1764; qq += 256) {     // 63 rows * 28 chunks of 8 el
            int row = qq / 28, k = qq - row*28;
            unsigned gi = chb + (unsigned)row*384u + (unsigned)k*8u;
            if (gi > TOT_ELEMS - 16u) gi = TOT_ELEMS - 16u;
            const uint* gp = (const uint*)(in + gi);   // 16B aligned
            uint d0 = gp[0], d1 = gp[1], d2 = gp[2], d3 = gp[3], d4 = gp[4];
            unsigned widx = (unsigned)row*224u + (unsigned)k*4u;
            uint4* w0 = (uint4*)&sbuf[widx];
            uint4* w1 = (uint4*)&sbuf[widx + 112u];
            *w0 = make_uint4(d0, d1, d2, d3);
            *w1 = make_uint4(ab2(d1,d0), ab2(d2,d1), ab2(d3,d2), ab2(d4,d3));
        }
        __syncthreads();

        const ushort* ap1 = atabF + (size_t)((PER_B ? (b*4 + c) : c) * 39) * 1024 + l*8;
        short8_t xA0, xA1, yA0, yA1;      // T1 A pipeline
        short8_t x20, x21, y20, y21;      // T2 A pipeline
        uint2v sE[12], sO[12];            // B double buffer
        uint baddr = baddr0;

        ISSUE_B(sE, baddr); baddr += 896u;
        ISSUE_A(xA0, xA1, ap1, 0);

        // ---- P1: steps 0..7, T1 only ----
        ISSUE_B(sO, baddr); baddr += 896u;
        ISSUE_A(yA0, yA1, ap1, 1);
        STEP1B(sE, xA0, xA1, "2", "12");
        ISSUE_B(sE, baddr); baddr += 896u;
        ISSUE_A(xA0, xA1, ap1, 2);
        STEP1B(sO, yA0, yA1, "2", "12");
        ISSUE_B(sO, baddr); baddr += 896u;
        ISSUE_A(yA0, yA1, ap1, 3);
        STEP1B(sE, xA0, xA1, "2", "12");
        ISSUE_B(sE, baddr); baddr += 896u;
        ISSUE_A(xA0, xA1, ap1, 4);
        STEP1B(sO, yA0, yA1, "2", "12");
        ISSUE_B(sO, baddr); baddr += 896u;
        ISSUE_A(yA0, yA1, ap1, 5);
        STEP1B(sE, xA0, xA1, "2", "12");
        ISSUE_B(sE, baddr); baddr += 896u;
        ISSUE_A(xA0, xA1, ap1, 6);
        STEP1B(sO, yA0, yA1, "2", "12");
        ISSUE_B(sO, baddr); baddr += 896u;
        ISSUE_A(yA0, yA1, ap1, 7);
        STEP1B(sE, xA0, xA1, "2", "12");
        ISSUE_B(sE, baddr); baddr += 896u;
        ISSUE_A(xA0, xA1, ap1, 8);
        ISSUE_A(x20, x21, ap1, 0);
        STEP1B(sO, yA0, yA1, "4", "12");

        // ---- P2: steps 8..37, both tiles (T1 entry r, T2 entry r-8) ----
        #pragma unroll 1
        for (int t = 0; t < 15; ++t) {
            int r = 8 + 2*t;
            ISSUE_B(sO, baddr); baddr += 896u;
            ISSUE_A(yA0, yA1, ap1, r+1); ISSUE_A(y20, y21, ap1, r-7);
            STEP12B(sE, xA0, xA1, x20, x21, "4", "12");
            ISSUE_B(sE, baddr); baddr += 896u;
            ISSUE_A(xA0, xA1, ap1, r+2); ISSUE_A(x20, x21, ap1, r-6);
            STEP12B(sO, yA0, yA1, y20, y21, "4", "12");
        }
        // ---- step 38 ----
        ISSUE_B(sO, baddr); baddr += 896u;
        ISSUE_A(y20, y21, ap1, 31);
        STEP12B(sE, xA0, xA1, x20, x21, "2", "12");

        // ---- P3: steps 39..46, T2 only (entries 31..38) ----
        ISSUE_B(sE, baddr); baddr += 896u; ISSUE_A(x20, x21, ap1, 32); STEP2B(sO, y20, y21, "2", "12");
        ISSUE_B(sO, baddr); baddr += 896u; ISSUE_A(y20, y21, ap1, 33); STEP2B(sE, x20, x21, "2", "12");
        ISSUE_B(sE, baddr); baddr += 896u; ISSUE_A(x20, x21, ap1, 34); STEP2B(sO, y20, y21, "2", "12");
        ISSUE_B(sO, baddr); baddr += 896u; ISSUE_A(y20, y21, ap1, 35); STEP2B(sE, x20, x21, "2", "12");
        ISSUE_B(sE, baddr); baddr += 896u; ISSUE_A(x20, x21, ap1, 36); STEP2B(sO, y20, y21, "2", "12");
        ISSUE_B(sO, baddr); baddr += 896u; ISSUE_A(y20, y21, ap1, 37); STEP2B(sE, x20, x21, "2", "12");
        ISSUE_B(sE, baddr); baddr += 896u; ISSUE_A(x20, x21, ap1, 38); STEP2B(sO, y20, y21, "2", "12");
        STEP2B(sE, x20, x21, "0", "0");
    }

    float bv0 = 0.f, bv1 = 0.f, bv2 = 0.f, bv3 = 0.f;
    if (ADD_BIAS) { bv0 = bias[0]; bv1 = bias[1]; bv2 = bias[2]; bv3 = bias[3]; }

    #pragma unroll
    for (int j = 0; j < 3; j++) {
        int ox = x0 + xs + 32*j + (l & 31);
        if (ox > 352) continue;
        int px = ox + 15;
        #pragma unroll
        for (int rg = 0; rg < 16; rg++) {
            int m  = rg & 3;
            int dy = 2*(rg >> 2) + hi;
            float v1 = (j == 0 ? q0[rg] : (j == 1 ? q1[rg] : q2[rg]));
            float v2 = (j == 0 ? u0[rg] : (j == 1 ? u1[rg] : u2[rg]));
            float bb = (m == 0 ? bv0 : m == 1 ? bv1 : m == 2 ? bv2 : bv3);
            int oy1 = yv + rowoff + dy;
            if (oy1 <= 352) {
                size_t o = ((size_t)(b*4 + m))*HW + (size_t)(oy1 + 15)*HH + px;
                float v = v1 + (ADD_BIAS ? bb : 0.f);
                if constexpr (OUT_BF16) ((bf16*)outp)[o] = f2b(v);
                else                    ((float*)outp)[o] = v;
            }
            int oy2 = yv + rowoff + 8 + dy;
            if (oy2 <= 352) {
                size_t o = ((size_t)(b*4 + m))*HW + (size_t)(oy2 + 15)*HH + px;
                float v = v2 + (ADD_BIAS ? bb : 0.f);
                if constexpr (OUT_BF16) ((bf16*)outp)[o] = f2b(v);
                else                    ((float*)outp)[o] = v;
            }
        }
    }
}

extern "C" void kernel_launch(void* const* d_in, const int* in_sizes, int n_in,
                              void* d_out, int out_size, void* d_ws, size_t ws_size,
                              hipStream_t stream)
{
    const float* inputs = (const float*)d_in[0];
    const float* fm     = (const float*)d_in[1];
    const float* meta   = (const float*)d_in[2];
    const float* mcw    = (const float*)d_in[3];
    const float* mcb    = (const float*)d_in[4];
    const float* mlw    = (const float*)d_in[5];
    const float* mlb    = (const float*)d_in[6];
    const float* icw    = (const float*)d_in[7];
    const float* icb    = (const float*)d_in[8];
    const float* bbw    = (const float*)d_in[9];
    const float* bbb    = (const float*)d_in[10];

    // workspace layout (bytes):
    //   ci     bf16 [32,4,384,384]      @ 0           37,748,736
    //   mapped bf16 [32,4,384,384]      @ 37,748,736  37,748,736
    //   cf     f32  [32,16,1024]        @ 75,497,472   2,097,152
    //   wts    bf16 [32,16,1024]        @ 77,594,624   1,048,576
    //   atab1F bf16 [32,4,39,2,64,8]    @ 78,643,200  10,223,616
    //   atab2F bf16 [4,39,2,64,8]       @ 88,866,816     319,488
    char* ws = (char*)d_ws;
    bf16*   ci     = (bf16*) ws;
    bf16*   mapped = (bf16*)(ws + 37748736);
    float*  cf     = (float*)(ws + 75497472);
    bf16*   wts    = (bf16*)(ws + 77594624);
    ushort* atab1F = (ushort*)(ws + 78643200);
    ushort* atab2F = (ushort*)(ws + 88866816);

    ci_kernel<<<18432, 256, 0, stream>>>(inputs, icw, icb, ci);
    convfeats_kernel<<<128, 256, 0, stream>>>(fm, mcw, mcb, cf);
    wts_kernel<<<512, 256, 0, stream>>>(meta, mlw, mlb, cf, wts);
    atab1F_kernel<<<2496, 256, 0, stream>>>((const ushort*)wts, atab1F);
    atab2F_kernel<<<78, 256, 0, stream>>>(bbw, atab2F);

    hipMemsetAsync(mapped, 0, 37748736, stream);
    conv32_quad<true, true, false><<<768, 256, 0, stream>>>(
        (const ushort*)ci, atab1F, nullptr, mapped);

    hipMemsetAsync(d_out, 0, (size_t)out_size * 4, stream);
    conv32_quad<false, false, true><<<768, 256, 0, stream>>>(
        (const ushort*)mapped, atab2F, bbb, d_out);
}